// Round 5
// baseline (289.074 us; speedup 1.0000x reference)
//
#include <hip/hip_runtime.h>
#include <math.h>

typedef unsigned short u16;
typedef unsigned int   u32;
typedef __bf16 bf16x8 __attribute__((ext_vector_type(8)));
typedef float  f32x4  __attribute__((ext_vector_type(4)));

// B=4 S=2048 D=1024 H=16 Dh=64 -> BH=64 chains, 32 chunks of 64
#define NBATCH 4
#define SEQ    2048
#define DIM    1024
#define NH     16
#define BH     64
#define NC     32
#define ROWS   8192
#define N1     3200   /* 3072 qkv cols + 48 gate cols padded to 128 */

__device__ __forceinline__ u16 f2bf(float f) {
  u32 u = __builtin_bit_cast(u32, f);
  u32 r = u + 0x7fffu + ((u >> 16) & 1u);
  return (u16)(r >> 16);
}
__device__ __forceinline__ float bf2f(u16 h) {
  return __builtin_bit_cast(float, (u32)h << 16);
}

// async global->LDS, 16B per lane; LDS dest = wave-uniform base + lane*16
__device__ __forceinline__ void gl2lds16(const u16* g, u16* l) {
  __builtin_amdgcn_global_load_lds(
      (const __attribute__((address_space(1))) u32*)g,
      (__attribute__((address_space(3))) u32*)l, 16, 0, 0);
}

// ---------------- weight transpose: Bt[n][k] = W[k][n], fp32 -> bf16 ----------------
__global__ __launch_bounds__(256) void transpose_w(const float* __restrict__ W,
                                                   u16* __restrict__ Bt, int K, int N) {
  __shared__ float tile[32][33];
  const int n0 = blockIdx.x * 32, k0 = blockIdx.y * 32;
  const int tx = threadIdx.x, ty = threadIdx.y;
  #pragma unroll
  for (int i = 0; i < 4; i++)
    tile[ty + i * 8][tx] = W[(size_t)(k0 + ty + i * 8) * N + n0 + tx];
  __syncthreads();
  #pragma unroll
  for (int i = 0; i < 4; i++)
    Bt[(size_t)(n0 + ty + i * 8) * K + k0 + tx] = f2bf(tile[tx][ty + i * 8]);
}

// rows 3072..3199 of wqkvT: gate weights (48 real cols) + zero pad
__global__ __launch_bounds__(256) void fill_gateW(const float* __restrict__ wg,
                                                  u16* __restrict__ Bt) {
  const int g = blockIdx.x;        // 0..127
  const int tid = threadIdx.x;
  #pragma unroll
  for (int kk = 0; kk < 4; kk++) {
    const int k = kk * 256 + tid;
    u16 v = 0;
    if (g < 48) v = f2bf(wg[(size_t)k * 48 + g]);
    Bt[(size_t)(3072 + g) * 1024 + k] = v;
  }
}

// ---------------- RMSNorm: x fp32 -> xn bf16 ----------------
__global__ __launch_bounds__(256) void rmsnorm_k(const float* __restrict__ x,
                                                 const float* __restrict__ w,
                                                 u16* __restrict__ xn) {
  const int row = blockIdx.x, tid = threadIdx.x;
  const float4 xv = *(const float4*)&x[(size_t)row * 1024 + tid * 4];
  float ss = xv.x * xv.x + xv.y * xv.y + xv.z * xv.z + xv.w * xv.w;
  #pragma unroll
  for (int off = 32; off > 0; off >>= 1) ss += __shfl_down(ss, off);
  __shared__ float red[4];
  if ((tid & 63) == 0) red[tid >> 6] = ss;
  __syncthreads();
  const float tot = red[0] + red[1] + red[2] + red[3];
  const float scale = rsqrtf(tot * (1.0f / 1024.0f) + 1e-6f);
  const float4 wv = *(const float4*)&w[tid * 4];
  const u16 o0 = f2bf(xv.x * scale * wv.x), o1 = f2bf(xv.y * scale * wv.y);
  const u16 o2 = f2bf(xv.z * scale * wv.z), o3 = f2bf(xv.w * scale * wv.w);
  uint2 ov;
  ov.x = (u32)o0 | ((u32)o1 << 16);
  ov.y = (u32)o2 | ((u32)o3 << 16);
  *(uint2*)&xn[(size_t)row * 1024 + tid * 4] = ov;
}

// ---------------- MFMA GEMM core: C(256x128) = A(256xK) @ Bt(128xK)^T, BK=64 ----------------
// 512 threads = 8 waves as 4 (rows) x 2 (cols) of 64x64 sub-tiles.
// Staging via global_load_lds width=16; LDS As[256*64], Bs[128*64] unpadded.
__device__ __forceinline__ void gemm_core256(const u16* __restrict__ A, const u16* __restrict__ Bt,
                                             int K, int rowBase, int colBase,
                                             u16* As, u16* Bs, f32x4 (&acc)[4][4]) {
  const int tid = threadIdx.x;
  const int lane = tid & 63;
  const int q = lane >> 4, m16 = lane & 15;
  const int wave = tid >> 6;
  const int wm = wave & 3, wn = wave >> 2;
  // As: 256 rows x 8 chunks = 2048 16B-chunks; Bs: 128 x 8 = 1024. chunk c -> row c>>3, col (c&7)*8
  const u16* gA[4]; u16* lA[4];
  const u16* gB[2]; u16* lB[2];
  #pragma unroll
  for (int j = 0; j < 4; j++) {
    const int c = tid + j * 512;
    gA[j] = &A[(size_t)(rowBase + (c >> 3)) * K + (c & 7) * 8];
    lA[j] = As + c * 8;
  }
  #pragma unroll
  for (int j = 0; j < 2; j++) {
    const int c = tid + j * 512;
    gB[j] = &Bt[(size_t)(colBase + (c >> 3)) * K + (c & 7) * 8];
    lB[j] = Bs + c * 8;
  }
  for (int kb = 0; kb < K / 64; ++kb) {
    __syncthreads();
    #pragma unroll
    for (int j = 0; j < 4; j++) { gl2lds16(gA[j], lA[j]); gA[j] += 64; }
    #pragma unroll
    for (int j = 0; j < 2; j++) { gl2lds16(gB[j], lB[j]); gB[j] += 64; }
    __syncthreads();
    #pragma unroll
    for (int ks = 0; ks < 2; ks++) {
      bf16x8 af[4], bfr[4];
      #pragma unroll
      for (int mi = 0; mi < 4; mi++)
        af[mi] = *(const bf16x8*)&As[(wm * 64 + mi * 16 + m16) * 64 + ks * 32 + q * 8];
      #pragma unroll
      for (int ni = 0; ni < 4; ni++)
        bfr[ni] = *(const bf16x8*)&Bs[(wn * 64 + ni * 16 + m16) * 64 + ks * 32 + q * 8];
      #pragma unroll
      for (int mi = 0; mi < 4; mi++)
        #pragma unroll
        for (int ni = 0; ni < 4; ni++)
          acc[mi][ni] = __builtin_amdgcn_mfma_f32_16x16x32_bf16(af[mi], bfr[ni], acc[mi][ni], 0, 0, 0);
    }
  }
}

// ---------------- MFMA GEMM core: C(128x128) = A(128xK) @ Bt(128xK)^T, BK=64 ----------------
// 256 threads = 4 waves as 2x2 of 64x64 sub-tiles. LDS As[128*64], Bs[128*64].
__device__ __forceinline__ void gemm_core128(const u16* __restrict__ A, const u16* __restrict__ Bt,
                                             int K, int rowBase, int colBase,
                                             u16* As, u16* Bs, f32x4 (&acc)[4][4]) {
  const int tid = threadIdx.x;
  const int lane = tid & 63;
  const int q = lane >> 4, m16 = lane & 15;
  const int wave = tid >> 6;
  const int wm = wave & 1, wn = wave >> 1;
  const u16* gA[4]; u16* lA[4];
  const u16* gB[4]; u16* lB[4];
  #pragma unroll
  for (int j = 0; j < 4; j++) {
    const int c = tid + j * 256;   // 1024 chunks each
    gA[j] = &A[(size_t)(rowBase + (c >> 3)) * K + (c & 7) * 8];
    lA[j] = As + c * 8;
    gB[j] = &Bt[(size_t)(colBase + (c >> 3)) * K + (c & 7) * 8];
    lB[j] = Bs + c * 8;
  }
  for (int kb = 0; kb < K / 64; ++kb) {
    __syncthreads();
    #pragma unroll
    for (int j = 0; j < 4; j++) { gl2lds16(gA[j], lA[j]); gA[j] += 64; }
    #pragma unroll
    for (int j = 0; j < 4; j++) { gl2lds16(gB[j], lB[j]); gB[j] += 64; }
    __syncthreads();
    #pragma unroll
    for (int ks = 0; ks < 2; ks++) {
      bf16x8 af[4], bfr[4];
      #pragma unroll
      for (int mi = 0; mi < 4; mi++)
        af[mi] = *(const bf16x8*)&As[(wm * 64 + mi * 16 + m16) * 64 + ks * 32 + q * 8];
      #pragma unroll
      for (int ni = 0; ni < 4; ni++)
        bfr[ni] = *(const bf16x8*)&Bs[(wn * 64 + ni * 16 + m16) * 64 + ks * 32 + q * 8];
      #pragma unroll
      for (int mi = 0; mi < 4; mi++)
        #pragma unroll
        for (int ni = 0; ni < 4; ni++)
          acc[mi][ni] = __builtin_amdgcn_mfma_f32_16x16x32_bf16(af[mi], bfr[ni], acc[mi][ni], 0, 0, 0);
    }
  }
}

// ---------------- GEMM1: qkv + gates ----------------
__global__ __launch_bounds__(512, 4) void gemm_qkv(const u16* __restrict__ A, const u16* __restrict__ Bt,
                                                   u16* __restrict__ Qb, u16* __restrict__ Kb,
                                                   u16* __restrict__ Vb, float* __restrict__ gates) {
  __shared__ __attribute__((aligned(16))) u16 As[256 * 64];
  __shared__ __attribute__((aligned(16))) u16 Bs[128 * 64];
  f32x4 acc[4][4] = {};
  const int rowBase = blockIdx.x * 256, colBase = blockIdx.y * 128;
  gemm_core256(A, Bt, 1024, rowBase, colBase, As, Bs, acc);
  const int tid = threadIdx.x;
  const int lane = tid & 63, wave = tid >> 6;
  const int q = lane >> 4, m16 = lane & 15;
  const int wm = wave & 3, wn = wave >> 2;
  __syncthreads();   // everyone done reading As before we reuse it as epilogue scratch
  if (colBase < 3072) {
    const int which = colBase >> 10;
    u16* dstBase = (which == 0) ? Qb : ((which == 1) ? Kb : Vb);
    const int b = rowBase >> 11;
    const int h = ((colBase & 1023) >> 6) + wn;
    const int tRow0 = (rowBase & 2047) + wm * 64;
    u16* scratch = As + wave * 1024;   // 16 rows x 64 cols bf16 per wave
    u16* headBase = dstBase + ((size_t)(b * 16 + h)) * 2048 * 64;
    const int rr = lane >> 2, co = (lane & 3) * 16;
    #pragma unroll
    for (int mi = 0; mi < 4; mi++) {
      #pragma unroll
      for (int ni = 0; ni < 4; ni++)
        #pragma unroll
        for (int r = 0; r < 4; r++)
          scratch[(q * 4 + r) * 64 + ni * 16 + m16] = f2bf(acc[mi][ni][r]);
      // wave-local LDS dependency; compiler inserts lgkmcnt wait
      const uint4 d0 = *(const uint4*)&scratch[rr * 64 + co];
      const uint4 d1 = *(const uint4*)&scratch[rr * 64 + co + 8];
      u16* gp = headBase + (size_t)(tRow0 + mi * 16 + rr) * 64 + co;
      *(uint4*)gp = d0;
      *(uint4*)(gp + 8) = d1;
    }
  } else {
    // gates block: cols 3072..3199, only first 48 meaningful
    #pragma unroll
    for (int ni = 0; ni < 4; ni++) {
      const int c2 = wn * 64 + ni * 16 + m16;
      if (c2 < 48) {
        const int which = c2 >> 4, hh = c2 & 15;
        #pragma unroll
        for (int mi = 0; mi < 4; mi++)
          #pragma unroll
          for (int r = 0; r < 4; r++) {
            const int grow = rowBase + wm * 64 + mi * 16 + q * 4 + r;
            const int b = grow >> 11, t = grow & 2047;
            const float v = acc[mi][ni][r];
            const float g = 1.0f / (1.0f + expf(-(15.0f * tanhf(v * (1.0f / 15.0f)))));
            gates[((size_t)which * 64 + (b * 16 + hh)) * 2048 + t] = g;
          }
      }
    }
  }
}

// ---------------- GEMM2: out = hseq @ woutT + residual ----------------
__global__ __launch_bounds__(256, 4) void gemm_out(const u16* __restrict__ A, const u16* __restrict__ Bt,
                                                   const float* __restrict__ resid,
                                                   float* __restrict__ out) {
  __shared__ __attribute__((aligned(16))) u16 As[128 * 64];
  __shared__ __attribute__((aligned(16))) u16 Bs[128 * 64];
  f32x4 acc[4][4] = {};
  const int rowBase = blockIdx.x * 128, colBase = blockIdx.y * 128;
  gemm_core128(A, Bt, 1024, rowBase, colBase, As, Bs, acc);
  const int tid = threadIdx.x;
  const int lane = tid & 63, wave = tid >> 6;
  const int q = lane >> 4, m16 = lane & 15;
  const int wm = wave & 1, wn = wave >> 1;
  #pragma unroll
  for (int mi = 0; mi < 4; mi++)
    #pragma unroll
    for (int ni = 0; ni < 4; ni++)
      #pragma unroll
      for (int r = 0; r < 4; r++) {
        const int grow = rowBase + wm * 64 + mi * 16 + q * 4 + r;
        const int gcol = colBase + wn * 64 + ni * 16 + m16;
        const size_t idx = (size_t)grow * 1024 + gcol;
        out[idx] = acc[mi][ni][r] + resid[idx];
      }
}

// ---------------- cumulative log-f within each 64-chunk ----------------
__global__ __launch_bounds__(64) void la_k(const float* __restrict__ gates,
                                           float* __restrict__ la) {
  const int bh = blockIdx.x >> 5, c = blockIdx.x & 31, lane = threadIdx.x;
  const int t = c * 64 + lane;
  float x = logf(gates[(size_t)(64 + bh) * 2048 + t]);  // f-gate (which=1)
  #pragma unroll
  for (int off = 1; off < 64; off <<= 1) {
    const float y = __shfl_up(x, off);
    if (lane >= off) x += y;
  }
  la[(size_t)bh * 2048 + t] = x;
}

// ---------------- pass A: intra-chunk attention + chunk state increment M ----------------
__global__ __launch_bounds__(256) void passA_k(const u16* __restrict__ Qb, const u16* __restrict__ Kb,
                                               const u16* __restrict__ Vb,
                                               const float* __restrict__ gates,
                                               const float* __restrict__ la,
                                               float* __restrict__ Mbuf, u16* __restrict__ hseq) {
  __shared__ u16 Ql[64][72], Kl[64][72], KTl[64][72], VTl[64][72], Pl[64][72];
  __shared__ float laS[64], iS[64];
  const int tid = threadIdx.x;
  const int bh = blockIdx.x >> 5, c = blockIdx.x & 31;
  const int lane = tid & 63, w = tid >> 6;
  const int q = lane >> 4, m16 = lane & 15;
  const size_t base = ((size_t)bh * 2048 + c * 64) * 64;
  const int tbase = bh * 2048 + c * 64;

  {
    const int s = tid >> 2, db = (tid & 3) * 16;
    if (tid < 64) {
      laS[tid] = la[tbase + tid];
      iS[tid] = gates[(size_t)bh * 2048 + c * 64 + tid];  // i-gate (which=0)
    }
    const float la_s = la[tbase + s];
    const float i_s = gates[(size_t)bh * 2048 + c * 64 + s];
    const float la63 = la[tbase + 63];
    const float wk = expf(la63 - la_s) * i_s;
    const uint4 q0 = *(const uint4*)&Qb[base + s * 64 + db];
    const uint4 q1 = *(const uint4*)&Qb[base + s * 64 + db + 8];
    *(uint4*)&Ql[s][db] = q0;
    *(uint4*)&Ql[s][db + 8] = q1;
    const uint4 k0 = *(const uint4*)&Kb[base + s * 64 + db];
    const uint4 k1 = *(const uint4*)&Kb[base + s * 64 + db + 8];
    *(uint4*)&Kl[s][db] = k0;
    *(uint4*)&Kl[s][db + 8] = k1;
    u16 ktmp[16];
    *(uint4*)&ktmp[0] = k0;
    *(uint4*)&ktmp[8] = k1;
    #pragma unroll
    for (int j = 0; j < 16; j++) KTl[db + j][s] = f2bf(wk * bf2f(ktmp[j]));
    const uint4 v0 = *(const uint4*)&Vb[base + s * 64 + db];
    const uint4 v1 = *(const uint4*)&Vb[base + s * 64 + db + 8];
    u16 vtmp[16];
    *(uint4*)&vtmp[0] = v0;
    *(uint4*)&vtmp[8] = v1;
    #pragma unroll
    for (int j = 0; j < 16; j++) VTl[db + j][s] = vtmp[j];
  }
  __syncthreads();

  // P = (Q K^T) * decay-mask
  f32x4 pacc[4] = {};
  #pragma unroll
  for (int ks = 0; ks < 2; ks++) {
    const bf16x8 aq = *(const bf16x8*)&Ql[w * 16 + m16][ks * 32 + q * 8];
    #pragma unroll
    for (int ni = 0; ni < 4; ni++) {
      const bf16x8 bk = *(const bf16x8*)&Kl[ni * 16 + m16][ks * 32 + q * 8];
      pacc[ni] = __builtin_amdgcn_mfma_f32_16x16x32_bf16(aq, bk, pacc[ni], 0, 0, 0);
    }
  }
  #pragma unroll
  for (int ni = 0; ni < 4; ni++)
    #pragma unroll
    for (int r = 0; r < 4; r++) {
      const int tt = w * 16 + q * 4 + r, ss = ni * 16 + m16;
      float Wts = 0.0f;
      if (ss <= tt) Wts = expf(laS[tt] - laS[ss]) * iS[ss];
      Pl[tt][ss] = f2bf(pacc[ni][r] * Wts);
    }
  __syncthreads();

  // h_intra = P @ V ; M = K'(scaled)^T @ V
  f32x4 hacc[4] = {}, macc[4] = {};
  #pragma unroll
  for (int ks = 0; ks < 2; ks++) {
    const bf16x8 ap = *(const bf16x8*)&Pl[w * 16 + m16][ks * 32 + q * 8];
    const bf16x8 ak = *(const bf16x8*)&KTl[w * 16 + m16][ks * 32 + q * 8];
    #pragma unroll
    for (int ni = 0; ni < 4; ni++) {
      const bf16x8 bv = *(const bf16x8*)&VTl[ni * 16 + m16][ks * 32 + q * 8];
      hacc[ni] = __builtin_amdgcn_mfma_f32_16x16x32_bf16(ap, bv, hacc[ni], 0, 0, 0);
      macc[ni] = __builtin_amdgcn_mfma_f32_16x16x32_bf16(ak, bv, macc[ni], 0, 0, 0);
    }
  }
  const int b = bh >> 4, h = bh & 15;
  #pragma unroll
  for (int ni = 0; ni < 4; ni++)
    #pragma unroll
    for (int r = 0; r < 4; r++) {
      const int tt = w * 16 + q * 4 + r, e = ni * 16 + m16;
      const int tg = c * 64 + tt;
      hseq[((size_t)b * 2048 + tg) * 1024 + h * 64 + e] = f2bf(hacc[ni][r]);
      Mbuf[(((size_t)bh * 32 + c) * 64 + tt) * 64 + e] = macc[ni][r];
    }
}

// ---------------- pass B: inter-chunk state scan (in place: M[c] -> S_prev[c]) ----------------
// one float per thread; 64 bh * 16 element-blocks = 1024 blocks; prefetch next M
__global__ __launch_bounds__(256) void passB_k(float* __restrict__ Mbuf,
                                               const float* __restrict__ hidden,
                                               const float* __restrict__ la) {
  const int bh = blockIdx.x >> 4;
  const int e = (blockIdx.x & 15) * 256 + threadIdx.x;
  __shared__ float Gs[32];
  if (threadIdx.x < 32)
    Gs[threadIdx.x] = expf(la[(size_t)bh * 2048 + threadIdx.x * 64 + 63]);
  __syncthreads();
  float st = hidden[(size_t)bh * 4096 + e];
  float* M = &Mbuf[(size_t)bh * 32 * 4096 + e];
  float m_next = M[0];
  #pragma unroll 4
  for (int c = 0; c < 32; c++) {
    const float m_cur = m_next;
    if (c < 31) m_next = M[(size_t)(c + 1) * 4096];
    M[(size_t)c * 4096] = st;
    st = Gs[c] * st + m_cur;
  }
}

// ---------------- pass C: h = o * (h_intra + a_t * q^T S_prev) ----------------
__global__ __launch_bounds__(256) void passC_k(const u16* __restrict__ Qb,
                                               const float* __restrict__ Sprev,
                                               const float* __restrict__ la,
                                               const float* __restrict__ gates,
                                               u16* __restrict__ hseq) {
  __shared__ u16 aQl[64][72], STl[64][72];
  const int tid = threadIdx.x;
  const int bh = blockIdx.x >> 5, c = blockIdx.x & 31;
  const int lane = tid & 63, w = tid >> 6;
  const int q = lane >> 4, m16 = lane & 15;
  const size_t base = ((size_t)bh * 2048 + c * 64) * 64;
  const int tbase = bh * 2048 + c * 64;
  {
    const int s = tid >> 2, db = (tid & 3) * 16;
    const float a_s = expf(la[tbase + s]);
    const uint4 q0 = *(const uint4*)&Qb[base + s * 64 + db];
    const uint4 q1 = *(const uint4*)&Qb[base + s * 64 + db + 8];
    u16 qtmp[16];
    *(uint4*)&qtmp[0] = q0;
    *(uint4*)&qtmp[8] = q1;
    #pragma unroll
    for (int j = 0; j < 16; j++) aQl[s][db + j] = f2bf(a_s * bf2f(qtmp[j]));
    const float* Sp = &Sprev[((size_t)bh * 32 + c) * 4096];
    #pragma unroll
    for (int j = 0; j < 16; j++) STl[db + j][s] = f2bf(Sp[s * 64 + db + j]);
  }
  __syncthreads();
  f32x4 acc[4] = {};
  #pragma unroll
  for (int ks = 0; ks < 2; ks++) {
    const bf16x8 a = *(const bf16x8*)&aQl[w * 16 + m16][ks * 32 + q * 8];
    #pragma unroll
    for (int ni = 0; ni < 4; ni++) {
      const bf16x8 bb = *(const bf16x8*)&STl[ni * 16 + m16][ks * 32 + q * 8];
      acc[ni] = __builtin_amdgcn_mfma_f32_16x16x32_bf16(a, bb, acc[ni], 0, 0, 0);
    }
  }
  const int b = bh >> 4, h = bh & 15;
  #pragma unroll
  for (int ni = 0; ni < 4; ni++)
    #pragma unroll
    for (int r = 0; r < 4; r++) {
      const int tt = w * 16 + q * 4 + r, e = ni * 16 + m16;
      const int tg = c * 64 + tt;
      const float o = gates[(size_t)(128 + bh) * 2048 + tg];  // o-gate (which=2)
      const size_t idx = ((size_t)b * 2048 + tg) * 1024 + h * 64 + e;
      hseq[idx] = f2bf(o * (bf2f(hseq[idx]) + acc[ni][r]));
    }
}

extern "C" void kernel_launch(void* const* d_in, const int* in_sizes, int n_in,
                              void* d_out, int out_size, void* d_ws, size_t ws_size,
                              hipStream_t stream) {
  (void)in_sizes; (void)n_in; (void)out_size; (void)ws_size;
  const float* x      = (const float*)d_in[0];
  const float* hidden = (const float*)d_in[1];
  const float* w_rms  = (const float*)d_in[2];
  const float* w_qkv  = (const float*)d_in[3];
  const float* w_gate = (const float*)d_in[4];
  const float* w_out  = (const float*)d_in[5];
  float* out = (float*)d_out;

  char* p = (char*)d_ws;
  u16* wqkvT = (u16*)p;  p += (size_t)N1 * 1024 * 2;        // 6.55 MB
  u16* woutT = (u16*)p;  p += (size_t)1024 * 1024 * 2;      // 2.1 MB
  u16* xn    = (u16*)p;  p += (size_t)ROWS * 1024 * 2;      // 16.8 MB
  u16* Qb    = (u16*)p;  p += (size_t)BH * 2048 * 64 * 2;   // 16.8 MB
  u16* Kb    = (u16*)p;  p += (size_t)BH * 2048 * 64 * 2;
  u16* Vb    = (u16*)p;  p += (size_t)BH * 2048 * 64 * 2;
  float* gates = (float*)p; p += (size_t)3 * BH * 2048 * 4; // 1.6 MB
  float* la    = (float*)p; p += (size_t)BH * 2048 * 4;     // 0.5 MB
  float* Mbuf  = (float*)p; p += (size_t)BH * NC * 4096 * 4;// 33.6 MB
  u16* hseq  = (u16*)p;  p += (size_t)ROWS * 1024 * 2;      // 16.8 MB

  transpose_w<<<dim3(96, 32), dim3(32, 8), 0, stream>>>(w_qkv, wqkvT, 1024, 3072);
  transpose_w<<<dim3(32, 32), dim3(32, 8), 0, stream>>>(w_out, woutT, 1024, 1024);
  fill_gateW<<<128, 256, 0, stream>>>(w_gate, wqkvT);
  rmsnorm_k<<<ROWS, 256, 0, stream>>>(x, w_rms, xn);
  gemm_qkv<<<dim3(32, 25), 512, 0, stream>>>(xn, wqkvT, Qb, Kb, Vb, gates);
  la_k<<<BH * NC, 64, 0, stream>>>(gates, la);
  passA_k<<<BH * NC, 256, 0, stream>>>(Qb, Kb, Vb, gates, la, Mbuf, hseq);
  passB_k<<<BH * 16, 256, 0, stream>>>(Mbuf, hidden, la);
  passC_k<<<BH * NC, 256, 0, stream>>>(Qb, Mbuf, la, gates, hseq);
  gemm_out<<<dim3(64, 8), 256, 0, stream>>>(hseq, woutT, x, out);
}

// Round 6
// 269.590 us; speedup vs baseline: 1.0723x; 1.0723x over previous
//
#include <hip/hip_runtime.h>
#include <math.h>

typedef unsigned short u16;
typedef unsigned int   u32;
typedef __bf16 bf16x8 __attribute__((ext_vector_type(8)));
typedef float  f32x4  __attribute__((ext_vector_type(4)));

// B=4 S=2048 D=1024 H=16 Dh=64 -> BH=64 chains, 32 chunks of 64
#define NBATCH 4
#define SEQ    2048
#define DIM    1024
#define NH     16
#define BH     64
#define NC     32
#define ROWS   8192
#define N1     3200   /* 3072 qkv cols + 48 gate cols padded to 128 */

__device__ __forceinline__ u16 f2bf(float f) {
  u32 u = __builtin_bit_cast(u32, f);
  u32 r = u + 0x7fffu + ((u >> 16) & 1u);
  return (u16)(r >> 16);
}
__device__ __forceinline__ float bf2f(u16 h) {
  return __builtin_bit_cast(float, (u32)h << 16);
}

// async global->LDS, 16B per lane; LDS dest = wave-uniform base + lane*16
__device__ __forceinline__ void gl2lds16(const u16* g, u16* l) {
  __builtin_amdgcn_global_load_lds(
      (const __attribute__((address_space(1))) u32*)g,
      (__attribute__((address_space(3))) u32*)l, 16, 0, 0);
}

// ---------------- weight transpose: Bt[n][k] = W[k][n], fp32 -> bf16 ----------------
__global__ __launch_bounds__(256) void transpose_w(const float* __restrict__ W,
                                                   u16* __restrict__ Bt, int K, int N) {
  __shared__ float tile[32][33];
  const int n0 = blockIdx.x * 32, k0 = blockIdx.y * 32;
  const int tx = threadIdx.x, ty = threadIdx.y;
  #pragma unroll
  for (int i = 0; i < 4; i++)
    tile[ty + i * 8][tx] = W[(size_t)(k0 + ty + i * 8) * N + n0 + tx];
  __syncthreads();
  #pragma unroll
  for (int i = 0; i < 4; i++)
    Bt[(size_t)(n0 + ty + i * 8) * K + k0 + tx] = f2bf(tile[tx][ty + i * 8]);
}

// rows 3072..3199 of wqkvT: gate weights (48 real cols) + zero pad
__global__ __launch_bounds__(256) void fill_gateW(const float* __restrict__ wg,
                                                  u16* __restrict__ Bt) {
  const int g = blockIdx.x;        // 0..127
  const int tid = threadIdx.x;
  #pragma unroll
  for (int kk = 0; kk < 4; kk++) {
    const int k = kk * 256 + tid;
    u16 v = 0;
    if (g < 48) v = f2bf(wg[(size_t)k * 48 + g]);
    Bt[(size_t)(3072 + g) * 1024 + k] = v;
  }
}

// ---------------- RMSNorm: x fp32 -> xn bf16 ----------------
__global__ __launch_bounds__(256) void rmsnorm_k(const float* __restrict__ x,
                                                 const float* __restrict__ w,
                                                 u16* __restrict__ xn) {
  const int row = blockIdx.x, tid = threadIdx.x;
  const float4 xv = *(const float4*)&x[(size_t)row * 1024 + tid * 4];
  float ss = xv.x * xv.x + xv.y * xv.y + xv.z * xv.z + xv.w * xv.w;
  #pragma unroll
  for (int off = 32; off > 0; off >>= 1) ss += __shfl_down(ss, off);
  __shared__ float red[4];
  if ((tid & 63) == 0) red[tid >> 6] = ss;
  __syncthreads();
  const float tot = red[0] + red[1] + red[2] + red[3];
  const float scale = rsqrtf(tot * (1.0f / 1024.0f) + 1e-6f);
  const float4 wv = *(const float4*)&w[tid * 4];
  const u16 o0 = f2bf(xv.x * scale * wv.x), o1 = f2bf(xv.y * scale * wv.y);
  const u16 o2 = f2bf(xv.z * scale * wv.z), o3 = f2bf(xv.w * scale * wv.w);
  uint2 ov;
  ov.x = (u32)o0 | ((u32)o1 << 16);
  ov.y = (u32)o2 | ((u32)o3 << 16);
  *(uint2*)&xn[(size_t)row * 1024 + tid * 4] = ov;
}

// ---------------- MFMA GEMM core: C(256x128) = A(256xK) @ Bt(128xK)^T, BK=64 ----------------
// 512 threads = 8 waves as 4 (rows) x 2 (cols) of 64x64 sub-tiles.
// global_load_lds width=16; XOR bank swizzle: row r, logical chunk c stored at
// physical chunk c^(r&7) -> b128 fragment reads hit all 32 banks uniformly.
__device__ __forceinline__ void gemm_core256(const u16* __restrict__ A, const u16* __restrict__ Bt,
                                             int K, int rowBase, int colBase,
                                             u16* As, u16* Bs, f32x4 (&acc)[4][4]) {
  const int tid = threadIdx.x;
  const int lane = tid & 63;
  const int q = lane >> 4, m16 = lane & 15;
  const int wave = tid >> 6;
  const int wm = wave & 3, wn = wave >> 2;
  const int sw = m16 & 7;   // swizzle selector for fragment reads (row&7 == m16&7)
  // As: 256 rows x 8 chunks = 2048 16B-chunks; Bs: 128 x 8 = 1024.
  const u16* gA[4]; u16* lA[4];
  const u16* gB[2]; u16* lB[2];
  #pragma unroll
  for (int j = 0; j < 4; j++) {
    const int c = tid + j * 512;
    const int row = c >> 3, lc = (c & 7) ^ (row & 7);
    gA[j] = &A[(size_t)(rowBase + row) * K + lc * 8];
    lA[j] = As + c * 8;
  }
  #pragma unroll
  for (int j = 0; j < 2; j++) {
    const int c = tid + j * 512;
    const int row = c >> 3, lc = (c & 7) ^ (row & 7);
    gB[j] = &Bt[(size_t)(colBase + row) * K + lc * 8];
    lB[j] = Bs + c * 8;
  }
  for (int kb = 0; kb < K / 64; ++kb) {
    __syncthreads();
    #pragma unroll
    for (int j = 0; j < 4; j++) { gl2lds16(gA[j], lA[j]); gA[j] += 64; }
    #pragma unroll
    for (int j = 0; j < 2; j++) { gl2lds16(gB[j], lB[j]); gB[j] += 64; }
    __syncthreads();
    #pragma unroll
    for (int ks = 0; ks < 2; ks++) {
      const int co = ((ks * 4 + q) ^ sw) * 8;
      bf16x8 af[4], bfr[4];
      #pragma unroll
      for (int mi = 0; mi < 4; mi++)
        af[mi] = *(const bf16x8*)&As[(wm * 64 + mi * 16 + m16) * 64 + co];
      #pragma unroll
      for (int ni = 0; ni < 4; ni++)
        bfr[ni] = *(const bf16x8*)&Bs[(wn * 64 + ni * 16 + m16) * 64 + co];
      #pragma unroll
      for (int mi = 0; mi < 4; mi++)
        #pragma unroll
        for (int ni = 0; ni < 4; ni++)
          acc[mi][ni] = __builtin_amdgcn_mfma_f32_16x16x32_bf16(af[mi], bfr[ni], acc[mi][ni], 0, 0, 0);
    }
  }
}

// ---------------- MFMA GEMM core: C(128x128), BK=64, swizzled ----------------
// 256 threads = 4 waves as 2x2 of 64x64 sub-tiles. LDS As[128*64], Bs[128*64].
__device__ __forceinline__ void gemm_core128(const u16* __restrict__ A, const u16* __restrict__ Bt,
                                             int K, int rowBase, int colBase,
                                             u16* As, u16* Bs, f32x4 (&acc)[4][4]) {
  const int tid = threadIdx.x;
  const int lane = tid & 63;
  const int q = lane >> 4, m16 = lane & 15;
  const int wave = tid >> 6;
  const int wm = wave & 1, wn = wave >> 1;
  const int sw = m16 & 7;
  const u16* gA[4]; u16* lA[4];
  const u16* gB[4]; u16* lB[4];
  #pragma unroll
  for (int j = 0; j < 4; j++) {
    const int c = tid + j * 256;   // 1024 chunks each
    const int row = c >> 3, lc = (c & 7) ^ (row & 7);
    gA[j] = &A[(size_t)(rowBase + row) * K + lc * 8];
    lA[j] = As + c * 8;
    gB[j] = &Bt[(size_t)(colBase + row) * K + lc * 8];
    lB[j] = Bs + c * 8;
  }
  for (int kb = 0; kb < K / 64; ++kb) {
    __syncthreads();
    #pragma unroll
    for (int j = 0; j < 4; j++) { gl2lds16(gA[j], lA[j]); gA[j] += 64; }
    #pragma unroll
    for (int j = 0; j < 4; j++) { gl2lds16(gB[j], lB[j]); gB[j] += 64; }
    __syncthreads();
    #pragma unroll
    for (int ks = 0; ks < 2; ks++) {
      const int co = ((ks * 4 + q) ^ sw) * 8;
      bf16x8 af[4], bfr[4];
      #pragma unroll
      for (int mi = 0; mi < 4; mi++)
        af[mi] = *(const bf16x8*)&As[(wm * 64 + mi * 16 + m16) * 64 + co];
      #pragma unroll
      for (int ni = 0; ni < 4; ni++)
        bfr[ni] = *(const bf16x8*)&Bs[(wn * 64 + ni * 16 + m16) * 64 + co];
      #pragma unroll
      for (int mi = 0; mi < 4; mi++)
        #pragma unroll
        for (int ni = 0; ni < 4; ni++)
          acc[mi][ni] = __builtin_amdgcn_mfma_f32_16x16x32_bf16(af[mi], bfr[ni], acc[mi][ni], 0, 0, 0);
    }
  }
}

// ---------------- GEMM1: qkv + gates ----------------
__global__ __launch_bounds__(512, 4) void gemm_qkv(const u16* __restrict__ A, const u16* __restrict__ Bt,
                                                   u16* __restrict__ Qb, u16* __restrict__ Kb,
                                                   u16* __restrict__ Vb, float* __restrict__ gates) {
  __shared__ __attribute__((aligned(16))) u16 As[256 * 64];
  __shared__ __attribute__((aligned(16))) u16 Bs[128 * 64];
  f32x4 acc[4][4] = {};
  const int rowBase = blockIdx.x * 256, colBase = blockIdx.y * 128;
  gemm_core256(A, Bt, 1024, rowBase, colBase, As, Bs, acc);
  const int tid = threadIdx.x;
  const int lane = tid & 63, wave = tid >> 6;
  const int q = lane >> 4, m16 = lane & 15;
  const int wm = wave & 3, wn = wave >> 2;
  __syncthreads();   // everyone done reading As before we reuse it as epilogue scratch
  if (colBase < 3072) {
    const int which = colBase >> 10;
    u16* dstBase = (which == 0) ? Qb : ((which == 1) ? Kb : Vb);
    const int b = rowBase >> 11;
    const int h = ((colBase & 1023) >> 6) + wn;
    const int tRow0 = (rowBase & 2047) + wm * 64;
    u16* scratch = As + wave * 1024;   // 16 rows x 64 cols bf16 per wave
    u16* headBase = dstBase + ((size_t)(b * 16 + h)) * 2048 * 64;
    const int rr = lane >> 2, co = (lane & 3) * 16;
    #pragma unroll
    for (int mi = 0; mi < 4; mi++) {
      #pragma unroll
      for (int ni = 0; ni < 4; ni++)
        #pragma unroll
        for (int r = 0; r < 4; r++)
          scratch[(q * 4 + r) * 64 + ni * 16 + m16] = f2bf(acc[mi][ni][r]);
      // wave-local LDS dependency; compiler inserts lgkmcnt wait
      const uint4 d0 = *(const uint4*)&scratch[rr * 64 + co];
      const uint4 d1 = *(const uint4*)&scratch[rr * 64 + co + 8];
      u16* gp = headBase + (size_t)(tRow0 + mi * 16 + rr) * 64 + co;
      *(uint4*)gp = d0;
      *(uint4*)(gp + 8) = d1;
    }
  } else {
    // gates block: cols 3072..3199, only first 48 meaningful
    #pragma unroll
    for (int ni = 0; ni < 4; ni++) {
      const int c2 = wn * 64 + ni * 16 + m16;
      if (c2 < 48) {
        const int which = c2 >> 4, hh = c2 & 15;
        #pragma unroll
        for (int mi = 0; mi < 4; mi++)
          #pragma unroll
          for (int r = 0; r < 4; r++) {
            const int grow = rowBase + wm * 64 + mi * 16 + q * 4 + r;
            const int b = grow >> 11, t = grow & 2047;
            const float v = acc[mi][ni][r];
            const float g = 1.0f / (1.0f + expf(-(15.0f * tanhf(v * (1.0f / 15.0f)))));
            gates[((size_t)which * 64 + (b * 16 + hh)) * 2048 + t] = g;
          }
      }
    }
  }
}

// ---------------- GEMM2: out = hseq @ woutT + residual ----------------
__global__ __launch_bounds__(256, 4) void gemm_out(const u16* __restrict__ A, const u16* __restrict__ Bt,
                                                   const float* __restrict__ resid,
                                                   float* __restrict__ out) {
  __shared__ __attribute__((aligned(16))) u16 As[128 * 64];
  __shared__ __attribute__((aligned(16))) u16 Bs[128 * 64];
  f32x4 acc[4][4] = {};
  const int rowBase = blockIdx.x * 128, colBase = blockIdx.y * 128;
  gemm_core128(A, Bt, 1024, rowBase, colBase, As, Bs, acc);
  const int tid = threadIdx.x;
  const int lane = tid & 63, wave = tid >> 6;
  const int q = lane >> 4, m16 = lane & 15;
  const int wm = wave & 1, wn = wave >> 1;
  #pragma unroll
  for (int mi = 0; mi < 4; mi++)
    #pragma unroll
    for (int ni = 0; ni < 4; ni++)
      #pragma unroll
      for (int r = 0; r < 4; r++) {
        const int grow = rowBase + wm * 64 + mi * 16 + q * 4 + r;
        const int gcol = colBase + wn * 64 + ni * 16 + m16;
        const size_t idx = (size_t)grow * 1024 + gcol;
        out[idx] = acc[mi][ni][r] + resid[idx];
      }
}

// ---------------- cumulative log-f within each 64-chunk ----------------
__global__ __launch_bounds__(64) void la_k(const float* __restrict__ gates,
                                           float* __restrict__ la) {
  const int bh = blockIdx.x >> 5, c = blockIdx.x & 31, lane = threadIdx.x;
  const int t = c * 64 + lane;
  float x = logf(gates[(size_t)(64 + bh) * 2048 + t]);  // f-gate (which=1)
  #pragma unroll
  for (int off = 1; off < 64; off <<= 1) {
    const float y = __shfl_up(x, off);
    if (lane >= off) x += y;
  }
  la[(size_t)bh * 2048 + t] = x;
}

// ---------------- pass A: intra-chunk attention + chunk state increment M ----------------
__global__ __launch_bounds__(256) void passA_k(const u16* __restrict__ Qb, const u16* __restrict__ Kb,
                                               const u16* __restrict__ Vb,
                                               const float* __restrict__ gates,
                                               const float* __restrict__ la,
                                               float* __restrict__ Mbuf, u16* __restrict__ hseq) {
  __shared__ u16 Ql[64][72], Kl[64][72], KTl[64][72], VTl[64][72], Pl[64][72];
  __shared__ float laS[64], iS[64];
  const int tid = threadIdx.x;
  const int bh = blockIdx.x >> 5, c = blockIdx.x & 31;
  const int lane = tid & 63, w = tid >> 6;
  const int q = lane >> 4, m16 = lane & 15;
  const size_t base = ((size_t)bh * 2048 + c * 64) * 64;
  const int tbase = bh * 2048 + c * 64;

  {
    const int s = tid >> 2, db = (tid & 3) * 16;
    if (tid < 64) {
      laS[tid] = la[tbase + tid];
      iS[tid] = gates[(size_t)bh * 2048 + c * 64 + tid];  // i-gate (which=0)
    }
    const float la_s = la[tbase + s];
    const float i_s = gates[(size_t)bh * 2048 + c * 64 + s];
    const float la63 = la[tbase + 63];
    const float wk = expf(la63 - la_s) * i_s;
    const uint4 q0 = *(const uint4*)&Qb[base + s * 64 + db];
    const uint4 q1 = *(const uint4*)&Qb[base + s * 64 + db + 8];
    *(uint4*)&Ql[s][db] = q0;
    *(uint4*)&Ql[s][db + 8] = q1;
    const uint4 k0 = *(const uint4*)&Kb[base + s * 64 + db];
    const uint4 k1 = *(const uint4*)&Kb[base + s * 64 + db + 8];
    *(uint4*)&Kl[s][db] = k0;
    *(uint4*)&Kl[s][db + 8] = k1;
    u16 ktmp[16];
    *(uint4*)&ktmp[0] = k0;
    *(uint4*)&ktmp[8] = k1;
    #pragma unroll
    for (int j = 0; j < 16; j++) KTl[db + j][s] = f2bf(wk * bf2f(ktmp[j]));
    const uint4 v0 = *(const uint4*)&Vb[base + s * 64 + db];
    const uint4 v1 = *(const uint4*)&Vb[base + s * 64 + db + 8];
    u16 vtmp[16];
    *(uint4*)&vtmp[0] = v0;
    *(uint4*)&vtmp[8] = v1;
    #pragma unroll
    for (int j = 0; j < 16; j++) VTl[db + j][s] = vtmp[j];
  }
  __syncthreads();

  // P = (Q K^T) * decay-mask
  f32x4 pacc[4] = {};
  #pragma unroll
  for (int ks = 0; ks < 2; ks++) {
    const bf16x8 aq = *(const bf16x8*)&Ql[w * 16 + m16][ks * 32 + q * 8];
    #pragma unroll
    for (int ni = 0; ni < 4; ni++) {
      const bf16x8 bk = *(const bf16x8*)&Kl[ni * 16 + m16][ks * 32 + q * 8];
      pacc[ni] = __builtin_amdgcn_mfma_f32_16x16x32_bf16(aq, bk, pacc[ni], 0, 0, 0);
    }
  }
  #pragma unroll
  for (int ni = 0; ni < 4; ni++)
    #pragma unroll
    for (int r = 0; r < 4; r++) {
      const int tt = w * 16 + q * 4 + r, ss = ni * 16 + m16;
      float Wts = 0.0f;
      if (ss <= tt) Wts = expf(laS[tt] - laS[ss]) * iS[ss];
      Pl[tt][ss] = f2bf(pacc[ni][r] * Wts);
    }
  __syncthreads();

  // h_intra = P @ V ; M = K'(scaled)^T @ V
  f32x4 hacc[4] = {}, macc[4] = {};
  #pragma unroll
  for (int ks = 0; ks < 2; ks++) {
    const bf16x8 ap = *(const bf16x8*)&Pl[w * 16 + m16][ks * 32 + q * 8];
    const bf16x8 ak = *(const bf16x8*)&KTl[w * 16 + m16][ks * 32 + q * 8];
    #pragma unroll
    for (int ni = 0; ni < 4; ni++) {
      const bf16x8 bv = *(const bf16x8*)&VTl[ni * 16 + m16][ks * 32 + q * 8];
      hacc[ni] = __builtin_amdgcn_mfma_f32_16x16x32_bf16(ap, bv, hacc[ni], 0, 0, 0);
      macc[ni] = __builtin_amdgcn_mfma_f32_16x16x32_bf16(ak, bv, macc[ni], 0, 0, 0);
    }
  }
  const int b = bh >> 4, h = bh & 15;
  #pragma unroll
  for (int ni = 0; ni < 4; ni++)
    #pragma unroll
    for (int r = 0; r < 4; r++) {
      const int tt = w * 16 + q * 4 + r, e = ni * 16 + m16;
      const int tg = c * 64 + tt;
      hseq[((size_t)b * 2048 + tg) * 1024 + h * 64 + e] = f2bf(hacc[ni][r]);
      Mbuf[(((size_t)bh * 32 + c) * 64 + tt) * 64 + e] = macc[ni][r];
    }
}

// ---------------- pass B: inter-chunk state scan (in place: M[c] -> S_prev[c]) ----------------
// one float per thread; 64 bh * 16 element-blocks = 1024 blocks; prefetch next M
__global__ __launch_bounds__(256) void passB_k(float* __restrict__ Mbuf,
                                               const float* __restrict__ hidden,
                                               const float* __restrict__ la) {
  const int bh = blockIdx.x >> 4;
  const int e = (blockIdx.x & 15) * 256 + threadIdx.x;
  __shared__ float Gs[32];
  if (threadIdx.x < 32)
    Gs[threadIdx.x] = expf(la[(size_t)bh * 2048 + threadIdx.x * 64 + 63]);
  __syncthreads();
  float st = hidden[(size_t)bh * 4096 + e];
  float* M = &Mbuf[(size_t)bh * 32 * 4096 + e];
  float m_next = M[0];
  #pragma unroll 4
  for (int c = 0; c < 32; c++) {
    const float m_cur = m_next;
    if (c < 31) m_next = M[(size_t)(c + 1) * 4096];
    M[(size_t)c * 4096] = st;
    st = Gs[c] * st + m_cur;
  }
}

// ---------------- pass C: h = o * (h_intra + a_t * q^T S_prev) ----------------
__global__ __launch_bounds__(256) void passC_k(const u16* __restrict__ Qb,
                                               const float* __restrict__ Sprev,
                                               const float* __restrict__ la,
                                               const float* __restrict__ gates,
                                               u16* __restrict__ hseq) {
  __shared__ u16 aQl[64][72], STl[64][72];
  const int tid = threadIdx.x;
  const int bh = blockIdx.x >> 5, c = blockIdx.x & 31;
  const int lane = tid & 63, w = tid >> 6;
  const int q = lane >> 4, m16 = lane & 15;
  const size_t base = ((size_t)bh * 2048 + c * 64) * 64;
  const int tbase = bh * 2048 + c * 64;
  {
    const int s = tid >> 2, db = (tid & 3) * 16;
    const float a_s = expf(la[tbase + s]);
    const uint4 q0 = *(const uint4*)&Qb[base + s * 64 + db];
    const uint4 q1 = *(const uint4*)&Qb[base + s * 64 + db + 8];
    u16 qtmp[16];
    *(uint4*)&qtmp[0] = q0;
    *(uint4*)&qtmp[8] = q1;
    #pragma unroll
    for (int j = 0; j < 16; j++) aQl[s][db + j] = f2bf(a_s * bf2f(qtmp[j]));
    const float* Sp = &Sprev[((size_t)bh * 32 + c) * 4096];
    #pragma unroll
    for (int j = 0; j < 16; j++) STl[db + j][s] = f2bf(Sp[s * 64 + db + j]);
  }
  __syncthreads();
  f32x4 acc[4] = {};
  #pragma unroll
  for (int ks = 0; ks < 2; ks++) {
    const bf16x8 a = *(const bf16x8*)&aQl[w * 16 + m16][ks * 32 + q * 8];
    #pragma unroll
    for (int ni = 0; ni < 4; ni++) {
      const bf16x8 bb = *(const bf16x8*)&STl[ni * 16 + m16][ks * 32 + q * 8];
      acc[ni] = __builtin_amdgcn_mfma_f32_16x16x32_bf16(a, bb, acc[ni], 0, 0, 0);
    }
  }
  const int b = bh >> 4, h = bh & 15;
  #pragma unroll
  for (int ni = 0; ni < 4; ni++)
    #pragma unroll
    for (int r = 0; r < 4; r++) {
      const int tt = w * 16 + q * 4 + r, e = ni * 16 + m16;
      const int tg = c * 64 + tt;
      const float o = gates[(size_t)(128 + bh) * 2048 + tg];  // o-gate (which=2)
      const size_t idx = ((size_t)b * 2048 + tg) * 1024 + h * 64 + e;
      hseq[idx] = f2bf(o * (bf2f(hseq[idx]) + acc[ni][r]));
    }
}

extern "C" void kernel_launch(void* const* d_in, const int* in_sizes, int n_in,
                              void* d_out, int out_size, void* d_ws, size_t ws_size,
                              hipStream_t stream) {
  (void)in_sizes; (void)n_in; (void)out_size; (void)ws_size;
  const float* x      = (const float*)d_in[0];
  const float* hidden = (const float*)d_in[1];
  const float* w_rms  = (const float*)d_in[2];
  const float* w_qkv  = (const float*)d_in[3];
  const float* w_gate = (const float*)d_in[4];
  const float* w_out  = (const float*)d_in[5];
  float* out = (float*)d_out;

  char* p = (char*)d_ws;
  u16* wqkvT = (u16*)p;  p += (size_t)N1 * 1024 * 2;        // 6.55 MB
  u16* woutT = (u16*)p;  p += (size_t)1024 * 1024 * 2;      // 2.1 MB
  u16* xn    = (u16*)p;  p += (size_t)ROWS * 1024 * 2;      // 16.8 MB
  u16* Qb    = (u16*)p;  p += (size_t)BH * 2048 * 64 * 2;   // 16.8 MB
  u16* Kb    = (u16*)p;  p += (size_t)BH * 2048 * 64 * 2;
  u16* Vb    = (u16*)p;  p += (size_t)BH * 2048 * 64 * 2;
  float* gates = (float*)p; p += (size_t)3 * BH * 2048 * 4; // 1.6 MB
  float* la    = (float*)p; p += (size_t)BH * 2048 * 4;     // 0.5 MB
  float* Mbuf  = (float*)p; p += (size_t)BH * NC * 4096 * 4;// 33.6 MB
  u16* hseq  = (u16*)p;  p += (size_t)ROWS * 1024 * 2;      // 16.8 MB

  transpose_w<<<dim3(96, 32), dim3(32, 8), 0, stream>>>(w_qkv, wqkvT, 1024, 3072);
  transpose_w<<<dim3(32, 32), dim3(32, 8), 0, stream>>>(w_out, woutT, 1024, 1024);
  fill_gateW<<<128, 256, 0, stream>>>(w_gate, wqkvT);
  rmsnorm_k<<<ROWS, 256, 0, stream>>>(x, w_rms, xn);
  gemm_qkv<<<dim3(32, 25), 512, 0, stream>>>(xn, wqkvT, Qb, Kb, Vb, gates);
  la_k<<<BH * NC, 64, 0, stream>>>(gates, la);
  passA_k<<<BH * NC, 256, 0, stream>>>(Qb, Kb, Vb, gates, la, Mbuf, hseq);
  passB_k<<<BH * 16, 256, 0, stream>>>(Mbuf, hidden, la);
  passC_k<<<BH * NC, 256, 0, stream>>>(Qb, Mbuf, la, gates, hseq);
  gemm_out<<<dim3(64, 8), 256, 0, stream>>>(hseq, woutT, x, out);
}

// Round 8
// 269.159 us; speedup vs baseline: 1.0740x; 1.0016x over previous
//
#include <hip/hip_runtime.h>
#include <math.h>

typedef unsigned short u16;
typedef unsigned int   u32;
typedef __bf16 bf16x8 __attribute__((ext_vector_type(8)));
typedef float  f32x4  __attribute__((ext_vector_type(4)));

// B=4 S=2048 D=1024 H=16 Dh=64 -> BH=64 chains, 32 chunks of 64
#define NBATCH 4
#define SEQ    2048
#define DIM    1024
#define NH     16
#define BH     64
#define NC     32
#define ROWS   8192
#define N1     3200   /* 3072 qkv cols + 48 gate cols padded to 128 */

__device__ __forceinline__ u16 f2bf(float f) {
  u32 u = __builtin_bit_cast(u32, f);
  u32 r = u + 0x7fffu + ((u >> 16) & 1u);
  return (u16)(r >> 16);
}
__device__ __forceinline__ float bf2f(u16 h) {
  return __builtin_bit_cast(float, (u32)h << 16);
}

// async global->LDS, 16B per lane; LDS dest = wave-uniform base + lane*16
// NOTE: LDS layout is forced (lane-sequential); do NOT permute global order (r6 regression).
__device__ __forceinline__ void gl2lds16(const u16* g, u16* l) {
  __builtin_amdgcn_global_load_lds(
      (const __attribute__((address_space(1))) u32*)g,
      (__attribute__((address_space(3))) u32*)l, 16, 0, 0);
}

// ---------------- weight transpose: Bt[n][k] = W[k][n], fp32 -> bf16 ----------------
__global__ __launch_bounds__(256) void transpose_w(const float* __restrict__ W,
                                                   u16* __restrict__ Bt, int K, int N) {
  __shared__ float tile[32][33];
  const int n0 = blockIdx.x * 32, k0 = blockIdx.y * 32;
  const int tx = threadIdx.x, ty = threadIdx.y;
  #pragma unroll
  for (int i = 0; i < 4; i++)
    tile[ty + i * 8][tx] = W[(size_t)(k0 + ty + i * 8) * N + n0 + tx];
  __syncthreads();
  #pragma unroll
  for (int i = 0; i < 4; i++)
    Bt[(size_t)(n0 + ty + i * 8) * K + k0 + tx] = f2bf(tile[tx][ty + i * 8]);
}

// rows 3072..3199 of wqkvT: gate weights (48 real cols) + zero pad
__global__ __launch_bounds__(256) void fill_gateW(const float* __restrict__ wg,
                                                  u16* __restrict__ Bt) {
  const int g = blockIdx.x;        // 0..127
  const int tid = threadIdx.x;
  #pragma unroll
  for (int kk = 0; kk < 4; kk++) {
    const int k = kk * 256 + tid;
    u16 v = 0;
    if (g < 48) v = f2bf(wg[(size_t)k * 48 + g]);
    Bt[(size_t)(3072 + g) * 1024 + k] = v;
  }
}

// ---------------- RMSNorm: x fp32 -> xn bf16 ----------------
__global__ __launch_bounds__(256) void rmsnorm_k(const float* __restrict__ x,
                                                 const float* __restrict__ w,
                                                 u16* __restrict__ xn) {
  const int row = blockIdx.x, tid = threadIdx.x;
  const float4 xv = *(const float4*)&x[(size_t)row * 1024 + tid * 4];
  float ss = xv.x * xv.x + xv.y * xv.y + xv.z * xv.z + xv.w * xv.w;
  #pragma unroll
  for (int off = 32; off > 0; off >>= 1) ss += __shfl_down(ss, off);
  __shared__ float red[4];
  if ((tid & 63) == 0) red[tid >> 6] = ss;
  __syncthreads();
  const float tot = red[0] + red[1] + red[2] + red[3];
  const float scale = rsqrtf(tot * (1.0f / 1024.0f) + 1e-6f);
  const float4 wv = *(const float4*)&w[tid * 4];
  const u16 o0 = f2bf(xv.x * scale * wv.x), o1 = f2bf(xv.y * scale * wv.y);
  const u16 o2 = f2bf(xv.z * scale * wv.z), o3 = f2bf(xv.w * scale * wv.w);
  uint2 ov;
  ov.x = (u32)o0 | ((u32)o1 << 16);
  ov.y = (u32)o2 | ((u32)o3 << 16);
  *(uint2*)&xn[(size_t)row * 1024 + tid * 4] = ov;
}

// ---------------- MFMA GEMM core: C(256x128) = A(256xK) @ Bt(128xK)^T, BK=32 ----------------
// 512 threads = 8 waves as 4 (rows) x 2 (cols) of 64x64 sub-tiles.
// Staging via global_load_lds width=16; LDS As[256*32], Bs[128*32] unpadded. (round-4 best: 83us)
__device__ __forceinline__ void gemm_core256(const u16* __restrict__ A, const u16* __restrict__ Bt,
                                             int K, int rowBase, int colBase,
                                             u16* As, u16* Bs, f32x4 (&acc)[4][4]) {
  const int tid = threadIdx.x;
  const int lane = tid & 63;
  const int q = lane >> 4, m16 = lane & 15;
  const int wave = tid >> 6;
  const int wm = wave & 3, wn = wave >> 2;
  const int cA0 = tid;              // As rows 0..127
  const int cA1 = tid + 512;        // As rows 128..255
  const int cB  = tid;              // Bs rows 0..127
  const u16* gA0 = &A [(size_t)(rowBase + (cA0 >> 2)) * K + (cA0 & 3) * 8];
  const u16* gA1 = &A [(size_t)(rowBase + (cA1 >> 2)) * K + (cA1 & 3) * 8];
  const u16* gB  = &Bt[(size_t)(colBase + (cB  >> 2)) * K + (cB  & 3) * 8];
  u16* lA0 = As + cA0 * 8;
  u16* lA1 = As + cA1 * 8;
  u16* lB  = Bs + cB * 8;
  for (int kb = 0; kb < K / 32; ++kb) {
    __syncthreads();
    gl2lds16(gA0, lA0);
    gl2lds16(gA1, lA1);
    gl2lds16(gB,  lB);
    gA0 += 32; gA1 += 32; gB += 32;
    __syncthreads();
    bf16x8 af[4], bfr[4];
    #pragma unroll
    for (int mi = 0; mi < 4; mi++)
      af[mi] = *(const bf16x8*)&As[(wm * 64 + mi * 16 + m16) * 32 + q * 8];
    #pragma unroll
    for (int ni = 0; ni < 4; ni++)
      bfr[ni] = *(const bf16x8*)&Bs[(wn * 64 + ni * 16 + m16) * 32 + q * 8];
    #pragma unroll
    for (int mi = 0; mi < 4; mi++)
      #pragma unroll
      for (int ni = 0; ni < 4; ni++)
        acc[mi][ni] = __builtin_amdgcn_mfma_f32_16x16x32_bf16(af[mi], bfr[ni], acc[mi][ni], 0, 0, 0);
  }
}

// ---------------- MFMA GEMM core: C(128x128) = A(128xK) @ Bt(128xK)^T, BK=32 ----------------
// 256 threads = 4 waves as 2x2 of 64x64. LDS As[128*32], Bs[128*32] unpadded (m97 shape).
__device__ __forceinline__ void gemm_core128(const u16* __restrict__ A, const u16* __restrict__ Bt,
                                             int K, int rowBase, int colBase,
                                             u16* As, u16* Bs, f32x4 (&acc)[4][4]) {
  const int tid = threadIdx.x;
  const int lane = tid & 63;
  const int q = lane >> 4, m16 = lane & 15;
  const int wave = tid >> 6;
  const int wm = wave & 1, wn = wave >> 1;
  const int srow = wave * 16 + (lane >> 2);
  const int scol = (lane & 3) * 8;
  const u16* gA0 = &A [(size_t)(rowBase + srow) * K + scol];
  const u16* gA1 = gA0 + (size_t)64 * K;
  const u16* gB0 = &Bt[(size_t)(colBase + srow) * K + scol];
  const u16* gB1 = gB0 + (size_t)64 * K;
  u16* lA0 = As + wave * 512 + lane * 8;
  u16* lA1 = lA0 + 2048;
  u16* lB0 = Bs + wave * 512 + lane * 8;
  u16* lB1 = lB0 + 2048;
  for (int kb = 0; kb < K / 32; ++kb) {
    __syncthreads();
    gl2lds16(gA0, lA0);
    gl2lds16(gA1, lA1);
    gl2lds16(gB0, lB0);
    gl2lds16(gB1, lB1);
    gA0 += 32; gA1 += 32; gB0 += 32; gB1 += 32;
    __syncthreads();
    bf16x8 af[4], bfr[4];
    #pragma unroll
    for (int mi = 0; mi < 4; mi++)
      af[mi] = *(const bf16x8*)&As[(wm * 64 + mi * 16 + m16) * 32 + q * 8];
    #pragma unroll
    for (int ni = 0; ni < 4; ni++)
      bfr[ni] = *(const bf16x8*)&Bs[(wn * 64 + ni * 16 + m16) * 32 + q * 8];
    #pragma unroll
    for (int mi = 0; mi < 4; mi++)
      #pragma unroll
      for (int ni = 0; ni < 4; ni++)
        acc[mi][ni] = __builtin_amdgcn_mfma_f32_16x16x32_bf16(af[mi], bfr[ni], acc[mi][ni], 0, 0, 0);
  }
}

// ---------------- GEMM1: qkv + gates ----------------
__global__ __launch_bounds__(512, 4) void gemm_qkv(const u16* __restrict__ A, const u16* __restrict__ Bt,
                                                   u16* __restrict__ Qb, u16* __restrict__ Kb,
                                                   u16* __restrict__ Vb, float* __restrict__ gates) {
  __shared__ __attribute__((aligned(16))) u16 As[256 * 32];
  __shared__ __attribute__((aligned(16))) u16 Bs[128 * 32];
  f32x4 acc[4][4] = {};
  const int rowBase = blockIdx.x * 256, colBase = blockIdx.y * 128;
  gemm_core256(A, Bt, 1024, rowBase, colBase, As, Bs, acc);
  const int tid = threadIdx.x;
  const int lane = tid & 63, wave = tid >> 6;
  const int q = lane >> 4, m16 = lane & 15;
  const int wm = wave & 3, wn = wave >> 2;
  __syncthreads();   // everyone done reading As before we reuse it as epilogue scratch
  if (colBase < 3072) {
    const int which = colBase >> 10;
    u16* dstBase = (which == 0) ? Qb : ((which == 1) ? Kb : Vb);
    const int b = rowBase >> 11;
    const int h = ((colBase & 1023) >> 6) + wn;
    const int tRow0 = (rowBase & 2047) + wm * 64;
    u16* scratch = As + wave * 1024;   // 16 rows x 64 cols bf16 per wave
    u16* headBase = dstBase + ((size_t)(b * 16 + h)) * 2048 * 64;
    const int rr = lane >> 2, co = (lane & 3) * 16;
    #pragma unroll
    for (int mi = 0; mi < 4; mi++) {
      #pragma unroll
      for (int ni = 0; ni < 4; ni++)
        #pragma unroll
        for (int r = 0; r < 4; r++)
          scratch[(q * 4 + r) * 64 + ni * 16 + m16] = f2bf(acc[mi][ni][r]);
      // wave-local LDS dependency; compiler inserts lgkmcnt wait
      const uint4 d0 = *(const uint4*)&scratch[rr * 64 + co];
      const uint4 d1 = *(const uint4*)&scratch[rr * 64 + co + 8];
      u16* gp = headBase + (size_t)(tRow0 + mi * 16 + rr) * 64 + co;
      *(uint4*)gp = d0;
      *(uint4*)(gp + 8) = d1;
    }
  } else {
    // gates block: cols 3072..3199, only first 48 meaningful
    #pragma unroll
    for (int ni = 0; ni < 4; ni++) {
      const int c2 = wn * 64 + ni * 16 + m16;
      if (c2 < 48) {
        const int which = c2 >> 4, hh = c2 & 15;
        #pragma unroll
        for (int mi = 0; mi < 4; mi++)
          #pragma unroll
          for (int r = 0; r < 4; r++) {
            const int grow = rowBase + wm * 64 + mi * 16 + q * 4 + r;
            const int b = grow >> 11, t = grow & 2047;
            const float v = acc[mi][ni][r];
            const float g = 1.0f / (1.0f + expf(-(15.0f * tanhf(v * (1.0f / 15.0f)))));
            gates[((size_t)which * 64 + (b * 16 + hh)) * 2048 + t] = g;
          }
      }
    }
  }
}

// ---------------- GEMM2: out = hseq @ woutT + residual ----------------
__global__ __launch_bounds__(256, 4) void gemm_out(const u16* __restrict__ A, const u16* __restrict__ Bt,
                                                   const float* __restrict__ resid,
                                                   float* __restrict__ out) {
  __shared__ __attribute__((aligned(16))) u16 As[128 * 32];
  __shared__ __attribute__((aligned(16))) u16 Bs[128 * 32];
  f32x4 acc[4][4] = {};
  const int rowBase = blockIdx.x * 128, colBase = blockIdx.y * 128;
  gemm_core128(A, Bt, 1024, rowBase, colBase, As, Bs, acc);
  const int tid = threadIdx.x;
  const int lane = tid & 63, wave = tid >> 6;
  const int q = lane >> 4, m16 = lane & 15;
  const int wm = wave & 1, wn = wave >> 1;
  #pragma unroll
  for (int mi = 0; mi < 4; mi++)
    #pragma unroll
    for (int ni = 0; ni < 4; ni++)
      #pragma unroll
      for (int r = 0; r < 4; r++) {
        const int grow = rowBase + wm * 64 + mi * 16 + q * 4 + r;
        const int gcol = colBase + wn * 64 + ni * 16 + m16;
        const size_t idx = (size_t)grow * 1024 + gcol;
        out[idx] = acc[mi][ni][r] + resid[idx];
      }
}

// ---------------- pass A: la-scan + intra-chunk attention + chunk state increment M ----------------
__global__ __launch_bounds__(256) void passA_k(const u16* __restrict__ Qb, const u16* __restrict__ Kb,
                                               const u16* __restrict__ Vb,
                                               const float* __restrict__ gates,
                                               float* __restrict__ la,
                                               float* __restrict__ Mbuf, u16* __restrict__ hseq) {
  __shared__ u16 Ql[64][72], Kl[64][72], KTl[64][72], VTl[64][72], Pl[64][72];
  __shared__ float laS[64], iS[64];
  const int tid = threadIdx.x;
  const int bh = blockIdx.x >> 5, c = blockIdx.x & 31;
  const int lane = tid & 63, w = tid >> 6;
  const int q = lane >> 4, m16 = lane & 15;
  const size_t base = ((size_t)bh * 2048 + c * 64) * 64;
  const int toff = c * 64;   // time offset within the (bh) chain

  // wave 0: chunk-local cumulative log-f scan (fused la_k)
  if (tid < 64) {
    float lg = logf(gates[(size_t)(64 + bh) * 2048 + toff + tid]);  // f-gate
    #pragma unroll
    for (int off = 1; off < 64; off <<= 1) {
      const float y = __shfl_up(lg, off);
      if (tid >= off) lg += y;
    }
    laS[tid] = lg;
    iS[tid] = gates[(size_t)bh * 2048 + toff + tid];  // i-gate
    la[(size_t)bh * 2048 + toff + tid] = lg;          // for passB/passC
  }
  __syncthreads();

  {
    const int s = tid >> 2, db = (tid & 3) * 16;
    const float wk = expf(laS[63] - laS[s]) * iS[s];
    const uint4 q0 = *(const uint4*)&Qb[base + s * 64 + db];
    const uint4 q1 = *(const uint4*)&Qb[base + s * 64 + db + 8];
    *(uint4*)&Ql[s][db] = q0;
    *(uint4*)&Ql[s][db + 8] = q1;
    const uint4 k0 = *(const uint4*)&Kb[base + s * 64 + db];
    const uint4 k1 = *(const uint4*)&Kb[base + s * 64 + db + 8];
    *(uint4*)&Kl[s][db] = k0;
    *(uint4*)&Kl[s][db + 8] = k1;
    u16 ktmp[16];
    *(uint4*)&ktmp[0] = k0;
    *(uint4*)&ktmp[8] = k1;
    #pragma unroll
    for (int j = 0; j < 16; j++) KTl[db + j][s] = f2bf(wk * bf2f(ktmp[j]));
    const uint4 v0 = *(const uint4*)&Vb[base + s * 64 + db];
    const uint4 v1 = *(const uint4*)&Vb[base + s * 64 + db + 8];
    u16 vtmp[16];
    *(uint4*)&vtmp[0] = v0;
    *(uint4*)&vtmp[8] = v1;
    #pragma unroll
    for (int j = 0; j < 16; j++) VTl[db + j][s] = vtmp[j];
  }
  __syncthreads();

  // P = (Q K^T) * decay-mask
  f32x4 pacc[4] = {};
  #pragma unroll
  for (int ks = 0; ks < 2; ks++) {
    const bf16x8 aq = *(const bf16x8*)&Ql[w * 16 + m16][ks * 32 + q * 8];
    #pragma unroll
    for (int ni = 0; ni < 4; ni++) {
      const bf16x8 bk = *(const bf16x8*)&Kl[ni * 16 + m16][ks * 32 + q * 8];
      pacc[ni] = __builtin_amdgcn_mfma_f32_16x16x32_bf16(aq, bk, pacc[ni], 0, 0, 0);
    }
  }
  #pragma unroll
  for (int ni = 0; ni < 4; ni++)
    #pragma unroll
    for (int r = 0; r < 4; r++) {
      const int tt = w * 16 + q * 4 + r, ss = ni * 16 + m16;
      float Wts = 0.0f;
      if (ss <= tt) Wts = expf(laS[tt] - laS[ss]) * iS[ss];
      Pl[tt][ss] = f2bf(pacc[ni][r] * Wts);
    }
  __syncthreads();

  // h_intra = P @ V ; M = K'(scaled)^T @ V
  f32x4 hacc[4] = {}, macc[4] = {};
  #pragma unroll
  for (int ks = 0; ks < 2; ks++) {
    const bf16x8 ap = *(const bf16x8*)&Pl[w * 16 + m16][ks * 32 + q * 8];
    const bf16x8 ak = *(const bf16x8*)&KTl[w * 16 + m16][ks * 32 + q * 8];
    #pragma unroll
    for (int ni = 0; ni < 4; ni++) {
      const bf16x8 bv = *(const bf16x8*)&VTl[ni * 16 + m16][ks * 32 + q * 8];
      hacc[ni] = __builtin_amdgcn_mfma_f32_16x16x32_bf16(ap, bv, hacc[ni], 0, 0, 0);
      macc[ni] = __builtin_amdgcn_mfma_f32_16x16x32_bf16(ak, bv, macc[ni], 0, 0, 0);
    }
  }
  const int b = bh >> 4, h = bh & 15;
  #pragma unroll
  for (int ni = 0; ni < 4; ni++)
    #pragma unroll
    for (int r = 0; r < 4; r++) {
      const int tt = w * 16 + q * 4 + r, e = ni * 16 + m16;
      const int tg = c * 64 + tt;
      hseq[((size_t)b * 2048 + tg) * 1024 + h * 64 + e] = f2bf(hacc[ni][r]);
      Mbuf[(((size_t)bh * 32 + c) * 64 + tt) * 64 + e] = macc[ni][r];
    }
}

// ---------------- pass B: inter-chunk state scan (in place: M[c] -> S_prev[c]) ----------------
__global__ __launch_bounds__(256) void passB_k(float* __restrict__ Mbuf,
                                               const float* __restrict__ hidden,
                                               const float* __restrict__ la) {
  const int bh = blockIdx.x >> 4;
  const int e = (blockIdx.x & 15) * 256 + threadIdx.x;
  __shared__ float Gs[32];
  if (threadIdx.x < 32)
    Gs[threadIdx.x] = expf(la[(size_t)bh * 2048 + threadIdx.x * 64 + 63]);
  __syncthreads();
  float st = hidden[(size_t)bh * 4096 + e];
  float* M = &Mbuf[(size_t)bh * 32 * 4096 + e];
  float m_next = M[0];
  #pragma unroll 4
  for (int c = 0; c < 32; c++) {
    const float m_cur = m_next;
    if (c < 31) m_next = M[(size_t)(c + 1) * 4096];
    M[(size_t)c * 4096] = st;
    st = Gs[c] * st + m_cur;
  }
}

// ---------------- pass C: h = o * (h_intra + a_t * q^T S_prev) ----------------
__global__ __launch_bounds__(256) void passC_k(const u16* __restrict__ Qb,
                                               const float* __restrict__ Sprev,
                                               const float* __restrict__ la,
                                               const float* __restrict__ gates,
                                               u16* __restrict__ hseq) {
  __shared__ u16 aQl[64][72], STl[64][72];
  const int tid = threadIdx.x;
  const int bh = blockIdx.x >> 5, c = blockIdx.x & 31;
  const int lane = tid & 63, w = tid >> 6;
  const int q = lane >> 4, m16 = lane & 15;
  const size_t base = ((size_t)bh * 2048 + c * 64) * 64;
  const int tbase = bh * 2048 + c * 64;
  {
    const int s = tid >> 2, db = (tid & 3) * 16;
    const float a_s = expf(la[tbase + s]);
    const uint4 q0 = *(const uint4*)&Qb[base + s * 64 + db];
    const uint4 q1 = *(const uint4*)&Qb[base + s * 64 + db + 8];
    u16 qtmp[16];
    *(uint4*)&qtmp[0] = q0;
    *(uint4*)&qtmp[8] = q1;
    #pragma unroll
    for (int j = 0; j < 16; j++) aQl[s][db + j] = f2bf(a_s * bf2f(qtmp[j]));
    const float* Sp = &Sprev[((size_t)bh * 32 + c) * 4096];
    #pragma unroll
    for (int j = 0; j < 16; j++) STl[db + j][s] = f2bf(Sp[s * 64 + db + j]);
  }
  __syncthreads();
  f32x4 acc[4] = {};
  #pragma unroll
  for (int ks = 0; ks < 2; ks++) {
    const bf16x8 a = *(const bf16x8*)&aQl[w * 16 + m16][ks * 32 + q * 8];
    #pragma unroll
    for (int ni = 0; ni < 4; ni++) {
      const bf16x8 bb = *(const bf16x8*)&STl[ni * 16 + m16][ks * 32 + q * 8];
      acc[ni] = __builtin_amdgcn_mfma_f32_16x16x32_bf16(a, bb, acc[ni], 0, 0, 0);
    }
  }
  const int b = bh >> 4, h = bh & 15;
  #pragma unroll
  for (int ni = 0; ni < 4; ni++)
    #pragma unroll
    for (int r = 0; r < 4; r++) {
      const int tt = w * 16 + q * 4 + r, e = ni * 16 + m16;
      const int tg = c * 64 + tt;
      const float o = gates[(size_t)(128 + bh) * 2048 + tg];  // o-gate
      const size_t idx = ((size_t)b * 2048 + tg) * 1024 + h * 64 + e;
      hseq[idx] = f2bf(o * (bf2f(hseq[idx]) + acc[ni][r]));
    }
}

extern "C" void kernel_launch(void* const* d_in, const int* in_sizes, int n_in,
                              void* d_out, int out_size, void* d_ws, size_t ws_size,
                              hipStream_t stream) {
  (void)in_sizes; (void)n_in; (void)out_size; (void)ws_size;
  const float* x      = (const float*)d_in[0];
  const float* hidden = (const float*)d_in[1];
  const float* w_rms  = (const float*)d_in[2];
  const float* w_qkv  = (const float*)d_in[3];
  const float* w_gate = (const float*)d_in[4];
  const float* w_out  = (const float*)d_in[5];
  float* out = (float*)d_out;

  char* p = (char*)d_ws;
  u16* wqkvT = (u16*)p;  p += (size_t)N1 * 1024 * 2;        // 6.55 MB
  u16* woutT = (u16*)p;  p += (size_t)1024 * 1024 * 2;      // 2.1 MB
  u16* xn    = (u16*)p;  p += (size_t)ROWS * 1024 * 2;      // 16.8 MB
  u16* Qb    = (u16*)p;  p += (size_t)BH * 2048 * 64 * 2;   // 16.8 MB
  u16* Kb    = (u16*)p;  p += (size_t)BH * 2048 * 64 * 2;
  u16* Vb    = (u16*)p;  p += (size_t)BH * 2048 * 64 * 2;
  float* gates = (float*)p; p += (size_t)3 * BH * 2048 * 4; // 1.6 MB
  float* la    = (float*)p; p += (size_t)BH * 2048 * 4;     // 0.5 MB
  float* Mbuf  = (float*)p; p += (size_t)BH * NC * 4096 * 4;// 33.6 MB
  u16* hseq  = (u16*)p;  p += (size_t)ROWS * 1024 * 2;      // 16.8 MB

  transpose_w<<<dim3(96, 32), dim3(32, 8), 0, stream>>>(w_qkv, wqkvT, 1024, 3072);
  transpose_w<<<dim3(32, 32), dim3(32, 8), 0, stream>>>(w_out, woutT, 1024, 1024);
  fill_gateW<<<128, 256, 0, stream>>>(w_gate, wqkvT);
  rmsnorm_k<<<ROWS, 256, 0, stream>>>(x, w_rms, xn);
  gemm_qkv<<<dim3(32, 25), 512, 0, stream>>>(xn, wqkvT, Qb, Kb, Vb, gates);
  passA_k<<<BH * NC, 256, 0, stream>>>(Qb, Kb, Vb, gates, la, Mbuf, hseq);
  passB_k<<<BH * 16, 256, 0, stream>>>(Mbuf, hidden, la);
  passC_k<<<BH * NC, 256, 0, stream>>>(Qb, Mbuf, la, gates, hseq);
  gemm_out<<<dim3(64, 8), 256, 0, stream>>>(hseq, woutT, x, out);
}

// Round 9
// 268.143 us; speedup vs baseline: 1.0781x; 1.0038x over previous
//
#include <hip/hip_runtime.h>
#include <math.h>

typedef unsigned short u16;
typedef unsigned int   u32;
typedef __bf16 bf16x8 __attribute__((ext_vector_type(8)));
typedef float  f32x4  __attribute__((ext_vector_type(4)));

// B=4 S=2048 D=1024 H=16 Dh=64 -> BH=64 chains, 32 chunks of 64
#define NBATCH 4
#define SEQ    2048
#define DIM    1024
#define NH     16
#define BH     64
#define NC     32
#define ROWS   8192
#define N1     3200   /* 3072 qkv cols + 48 gate cols padded to 128 */

__device__ __forceinline__ u16 f2bf(float f) {
  u32 u = __builtin_bit_cast(u32, f);
  u32 r = u + 0x7fffu + ((u >> 16) & 1u);
  return (u16)(r >> 16);
}
__device__ __forceinline__ float bf2f(u16 h) {
  return __builtin_bit_cast(float, (u32)h << 16);
}

// async global->LDS, 16B per lane; LDS dest = wave-uniform base + lane*16
// NOTE: LDS layout is forced (lane-sequential); do NOT permute global order (r6 regression).
__device__ __forceinline__ void gl2lds16(const u16* g, u16* l) {
  __builtin_amdgcn_global_load_lds(
      (const __attribute__((address_space(1))) u32*)g,
      (__attribute__((address_space(3))) u32*)l, 16, 0, 0);
}

// ---------------- weight transpose: Bt[n][k] = W[k][n], fp32 -> bf16 ----------------
__global__ __launch_bounds__(256) void transpose_w(const float* __restrict__ W,
                                                   u16* __restrict__ Bt, int K, int N) {
  __shared__ float tile[32][33];
  const int n0 = blockIdx.x * 32, k0 = blockIdx.y * 32;
  const int tx = threadIdx.x, ty = threadIdx.y;
  #pragma unroll
  for (int i = 0; i < 4; i++)
    tile[ty + i * 8][tx] = W[(size_t)(k0 + ty + i * 8) * N + n0 + tx];
  __syncthreads();
  #pragma unroll
  for (int i = 0; i < 4; i++)
    Bt[(size_t)(n0 + ty + i * 8) * K + k0 + tx] = f2bf(tile[tx][ty + i * 8]);
}

// rows 3072..3199 of wqkvT: gate weights (48 real cols) + zero pad
__global__ __launch_bounds__(256) void fill_gateW(const float* __restrict__ wg,
                                                  u16* __restrict__ Bt) {
  const int g = blockIdx.x;        // 0..127
  const int tid = threadIdx.x;
  #pragma unroll
  for (int kk = 0; kk < 4; kk++) {
    const int k = kk * 256 + tid;
    u16 v = 0;
    if (g < 48) v = f2bf(wg[(size_t)k * 48 + g]);
    Bt[(size_t)(3072 + g) * 1024 + k] = v;
  }
}

// ---------------- RMSNorm: x fp32 -> xn bf16 ----------------
__global__ __launch_bounds__(256) void rmsnorm_k(const float* __restrict__ x,
                                                 const float* __restrict__ w,
                                                 u16* __restrict__ xn) {
  const int row = blockIdx.x, tid = threadIdx.x;
  const float4 xv = *(const float4*)&x[(size_t)row * 1024 + tid * 4];
  float ss = xv.x * xv.x + xv.y * xv.y + xv.z * xv.z + xv.w * xv.w;
  #pragma unroll
  for (int off = 32; off > 0; off >>= 1) ss += __shfl_down(ss, off);
  __shared__ float red[4];
  if ((tid & 63) == 0) red[tid >> 6] = ss;
  __syncthreads();
  const float tot = red[0] + red[1] + red[2] + red[3];
  const float scale = rsqrtf(tot * (1.0f / 1024.0f) + 1e-6f);
  const float4 wv = *(const float4*)&w[tid * 4];
  const u16 o0 = f2bf(xv.x * scale * wv.x), o1 = f2bf(xv.y * scale * wv.y);
  const u16 o2 = f2bf(xv.z * scale * wv.z), o3 = f2bf(xv.w * scale * wv.w);
  uint2 ov;
  ov.x = (u32)o0 | ((u32)o1 << 16);
  ov.y = (u32)o2 | ((u32)o3 << 16);
  *(uint2*)&xn[(size_t)row * 1024 + tid * 4] = ov;
}

// ---------------- MFMA GEMM core: C(256x128), BK=64 as 2x split-half BK=32 ----------------
// 512 threads = 8 waves as 4 (rows) x 2 (cols) of 64x64 sub-tiles.
// LDS: As = [half0: 256x32][half1: 256x32], Bs = [half0: 128x32][half1: 128x32].
// Each half keeps the round-4 64B row stride (conflict parity of r4), but one
// barrier-pair covers 64 K (half the barriers of r4). No swizzle (r6 lesson).
__device__ __forceinline__ void gemm_core256(const u16* __restrict__ A, const u16* __restrict__ Bt,
                                             int K, int rowBase, int colBase,
                                             u16* As, u16* Bs, f32x4 (&acc)[4][4]) {
  const int tid = threadIdx.x;
  const int lane = tid & 63;
  const int q = lane >> 4, m16 = lane & 15;
  const int wave = tid >> 6;
  const int wm = wave & 3, wn = wave >> 2;
  // A: 2048 chunks (half = c>>10, row = (c&1023)>>2, colchunk = c&3)
  const u16* gA[4]; u16* lA[4];
  const u16* gB[2]; u16* lB[2];
  #pragma unroll
  for (int j = 0; j < 4; j++) {
    const int c = tid + j * 512;
    const int half = c >> 10, cc = c & 1023;
    gA[j] = &A[(size_t)(rowBase + (cc >> 2)) * K + half * 32 + (cc & 3) * 8];
    lA[j] = As + c * 8;
  }
  // B: 1024 chunks (half = c>>9, row = (c&511)>>2)
  #pragma unroll
  for (int j = 0; j < 2; j++) {
    const int c = tid + j * 512;
    const int half = c >> 9, cc = c & 511;
    gB[j] = &Bt[(size_t)(colBase + (cc >> 2)) * K + half * 32 + (cc & 3) * 8];
    lB[j] = Bs + c * 8;
  }
  for (int kb = 0; kb < K / 64; ++kb) {
    __syncthreads();
    #pragma unroll
    for (int j = 0; j < 4; j++) { gl2lds16(gA[j], lA[j]); gA[j] += 64; }
    #pragma unroll
    for (int j = 0; j < 2; j++) { gl2lds16(gB[j], lB[j]); gB[j] += 64; }
    __syncthreads();
    #pragma unroll
    for (int ks = 0; ks < 2; ks++) {
      const int aoff = ks * 8192;   // 256*32
      const int boff = ks * 4096;   // 128*32
      bf16x8 af[4], bfr[4];
      #pragma unroll
      for (int mi = 0; mi < 4; mi++)
        af[mi] = *(const bf16x8*)&As[aoff + (wm * 64 + mi * 16 + m16) * 32 + q * 8];
      #pragma unroll
      for (int ni = 0; ni < 4; ni++)
        bfr[ni] = *(const bf16x8*)&Bs[boff + (wn * 64 + ni * 16 + m16) * 32 + q * 8];
      #pragma unroll
      for (int mi = 0; mi < 4; mi++)
        #pragma unroll
        for (int ni = 0; ni < 4; ni++)
          acc[mi][ni] = __builtin_amdgcn_mfma_f32_16x16x32_bf16(af[mi], bfr[ni], acc[mi][ni], 0, 0, 0);
    }
  }
}

// ---------------- MFMA GEMM core: C(128x128), BK=64 split-half, 256 threads ----------------
__device__ __forceinline__ void gemm_core128(const u16* __restrict__ A, const u16* __restrict__ Bt,
                                             int K, int rowBase, int colBase,
                                             u16* As, u16* Bs, f32x4 (&acc)[4][4]) {
  const int tid = threadIdx.x;
  const int lane = tid & 63;
  const int q = lane >> 4, m16 = lane & 15;
  const int wave = tid >> 6;
  const int wm = wave & 1, wn = wave >> 1;
  const u16* gA[4]; u16* lA[4];
  const u16* gB[4]; u16* lB[4];
  #pragma unroll
  for (int j = 0; j < 4; j++) {
    const int c = tid + j * 256;               // 1024 chunks each for A and B
    const int half = c >> 9, cc = c & 511;
    gA[j] = &A [(size_t)(rowBase + (cc >> 2)) * K + half * 32 + (cc & 3) * 8];
    lA[j] = As + c * 8;
    gB[j] = &Bt[(size_t)(colBase + (cc >> 2)) * K + half * 32 + (cc & 3) * 8];
    lB[j] = Bs + c * 8;
  }
  for (int kb = 0; kb < K / 64; ++kb) {
    __syncthreads();
    #pragma unroll
    for (int j = 0; j < 4; j++) { gl2lds16(gA[j], lA[j]); gA[j] += 64; }
    #pragma unroll
    for (int j = 0; j < 4; j++) { gl2lds16(gB[j], lB[j]); gB[j] += 64; }
    __syncthreads();
    #pragma unroll
    for (int ks = 0; ks < 2; ks++) {
      const int off = ks * 4096;   // 128*32
      bf16x8 af[4], bfr[4];
      #pragma unroll
      for (int mi = 0; mi < 4; mi++)
        af[mi] = *(const bf16x8*)&As[off + (wm * 64 + mi * 16 + m16) * 32 + q * 8];
      #pragma unroll
      for (int ni = 0; ni < 4; ni++)
        bfr[ni] = *(const bf16x8*)&Bs[off + (wn * 64 + ni * 16 + m16) * 32 + q * 8];
      #pragma unroll
      for (int mi = 0; mi < 4; mi++)
        #pragma unroll
        for (int ni = 0; ni < 4; ni++)
          acc[mi][ni] = __builtin_amdgcn_mfma_f32_16x16x32_bf16(af[mi], bfr[ni], acc[mi][ni], 0, 0, 0);
    }
  }
}

// ---------------- GEMM1: qkv + gates ----------------
__global__ __launch_bounds__(512, 4) void gemm_qkv(const u16* __restrict__ A, const u16* __restrict__ Bt,
                                                   u16* __restrict__ Qb, u16* __restrict__ Kb,
                                                   u16* __restrict__ Vb, float* __restrict__ gates) {
  __shared__ __attribute__((aligned(16))) u16 As[256 * 64];
  __shared__ __attribute__((aligned(16))) u16 Bs[128 * 64];
  f32x4 acc[4][4] = {};
  const int rowBase = blockIdx.x * 256, colBase = blockIdx.y * 128;
  gemm_core256(A, Bt, 1024, rowBase, colBase, As, Bs, acc);
  const int tid = threadIdx.x;
  const int lane = tid & 63, wave = tid >> 6;
  const int q = lane >> 4, m16 = lane & 15;
  const int wm = wave & 3, wn = wave >> 2;
  __syncthreads();   // everyone done reading As before we reuse it as epilogue scratch
  if (colBase < 3072) {
    const int which = colBase >> 10;
    u16* dstBase = (which == 0) ? Qb : ((which == 1) ? Kb : Vb);
    const int b = rowBase >> 11;
    const int h = ((colBase & 1023) >> 6) + wn;
    const int tRow0 = (rowBase & 2047) + wm * 64;
    u16* scratch = As + wave * 1024;   // 16 rows x 64 cols bf16 per wave
    u16* headBase = dstBase + ((size_t)(b * 16 + h)) * 2048 * 64;
    const int rr = lane >> 2, co = (lane & 3) * 16;
    #pragma unroll
    for (int mi = 0; mi < 4; mi++) {
      #pragma unroll
      for (int ni = 0; ni < 4; ni++)
        #pragma unroll
        for (int r = 0; r < 4; r++)
          scratch[(q * 4 + r) * 64 + ni * 16 + m16] = f2bf(acc[mi][ni][r]);
      // wave-local LDS dependency; compiler inserts lgkmcnt wait
      const uint4 d0 = *(const uint4*)&scratch[rr * 64 + co];
      const uint4 d1 = *(const uint4*)&scratch[rr * 64 + co + 8];
      u16* gp = headBase + (size_t)(tRow0 + mi * 16 + rr) * 64 + co;
      *(uint4*)gp = d0;
      *(uint4*)(gp + 8) = d1;
    }
  } else {
    // gates block: cols 3072..3199, only first 48 meaningful
    #pragma unroll
    for (int ni = 0; ni < 4; ni++) {
      const int c2 = wn * 64 + ni * 16 + m16;
      if (c2 < 48) {
        const int which = c2 >> 4, hh = c2 & 15;
        #pragma unroll
        for (int mi = 0; mi < 4; mi++)
          #pragma unroll
          for (int r = 0; r < 4; r++) {
            const int grow = rowBase + wm * 64 + mi * 16 + q * 4 + r;
            const int b = grow >> 11, t = grow & 2047;
            const float v = acc[mi][ni][r];
            const float g = 1.0f / (1.0f + expf(-(15.0f * tanhf(v * (1.0f / 15.0f)))));
            gates[((size_t)which * 64 + (b * 16 + hh)) * 2048 + t] = g;
          }
      }
    }
  }
}

// ---------------- GEMM2: out = hseq @ woutT + residual ----------------
__global__ __launch_bounds__(256, 4) void gemm_out(const u16* __restrict__ A, const u16* __restrict__ Bt,
                                                   const float* __restrict__ resid,
                                                   float* __restrict__ out) {
  __shared__ __attribute__((aligned(16))) u16 As[128 * 64];
  __shared__ __attribute__((aligned(16))) u16 Bs[128 * 64];
  f32x4 acc[4][4] = {};
  const int rowBase = blockIdx.x * 128, colBase = blockIdx.y * 128;
  gemm_core128(A, Bt, 1024, rowBase, colBase, As, Bs, acc);
  const int tid = threadIdx.x;
  const int lane = tid & 63, wave = tid >> 6;
  const int q = lane >> 4, m16 = lane & 15;
  const int wm = wave & 1, wn = wave >> 1;
  #pragma unroll
  for (int mi = 0; mi < 4; mi++)
    #pragma unroll
    for (int ni = 0; ni < 4; ni++)
      #pragma unroll
      for (int r = 0; r < 4; r++) {
        const int grow = rowBase + wm * 64 + mi * 16 + q * 4 + r;
        const int gcol = colBase + wn * 64 + ni * 16 + m16;
        const size_t idx = (size_t)grow * 1024 + gcol;
        out[idx] = acc[mi][ni][r] + resid[idx];
      }
}

// ---------------- pass A: la-scan + intra-chunk attention + chunk state increment M ----------------
__global__ __launch_bounds__(256) void passA_k(const u16* __restrict__ Qb, const u16* __restrict__ Kb,
                                               const u16* __restrict__ Vb,
                                               const float* __restrict__ gates,
                                               float* __restrict__ la,
                                               float* __restrict__ Mbuf, u16* __restrict__ hseq) {
  __shared__ u16 Ql[64][72], Kl[64][72], KTl[64][72], VTl[64][72], Pl[64][72];
  __shared__ float laS[64], iS[64];
  const int tid = threadIdx.x;
  const int bh = blockIdx.x >> 5, c = blockIdx.x & 31;
  const int lane = tid & 63, w = tid >> 6;
  const int q = lane >> 4, m16 = lane & 15;
  const size_t base = ((size_t)bh * 2048 + c * 64) * 64;
  const int toff = c * 64;   // time offset within the (bh) chain

  // wave 0: chunk-local cumulative log-f scan (fused la_k)
  if (tid < 64) {
    float lg = logf(gates[(size_t)(64 + bh) * 2048 + toff + tid]);  // f-gate
    #pragma unroll
    for (int off = 1; off < 64; off <<= 1) {
      const float y = __shfl_up(lg, off);
      if (tid >= off) lg += y;
    }
    laS[tid] = lg;
    iS[tid] = gates[(size_t)bh * 2048 + toff + tid];  // i-gate
    la[(size_t)bh * 2048 + toff + tid] = lg;          // for passB/passC
  }
  __syncthreads();

  {
    const int s = tid >> 2, db = (tid & 3) * 16;
    const float wk = expf(laS[63] - laS[s]) * iS[s];
    const uint4 q0 = *(const uint4*)&Qb[base + s * 64 + db];
    const uint4 q1 = *(const uint4*)&Qb[base + s * 64 + db + 8];
    *(uint4*)&Ql[s][db] = q0;
    *(uint4*)&Ql[s][db + 8] = q1;
    const uint4 k0 = *(const uint4*)&Kb[base + s * 64 + db];
    const uint4 k1 = *(const uint4*)&Kb[base + s * 64 + db + 8];
    *(uint4*)&Kl[s][db] = k0;
    *(uint4*)&Kl[s][db + 8] = k1;
    u16 ktmp[16];
    *(uint4*)&ktmp[0] = k0;
    *(uint4*)&ktmp[8] = k1;
    #pragma unroll
    for (int j = 0; j < 16; j++) KTl[db + j][s] = f2bf(wk * bf2f(ktmp[j]));
    const uint4 v0 = *(const uint4*)&Vb[base + s * 64 + db];
    const uint4 v1 = *(const uint4*)&Vb[base + s * 64 + db + 8];
    u16 vtmp[16];
    *(uint4*)&vtmp[0] = v0;
    *(uint4*)&vtmp[8] = v1;
    #pragma unroll
    for (int j = 0; j < 16; j++) VTl[db + j][s] = vtmp[j];
  }
  __syncthreads();

  // P = (Q K^T) * decay-mask
  f32x4 pacc[4] = {};
  #pragma unroll
  for (int ks = 0; ks < 2; ks++) {
    const bf16x8 aq = *(const bf16x8*)&Ql[w * 16 + m16][ks * 32 + q * 8];
    #pragma unroll
    for (int ni = 0; ni < 4; ni++) {
      const bf16x8 bk = *(const bf16x8*)&Kl[ni * 16 + m16][ks * 32 + q * 8];
      pacc[ni] = __builtin_amdgcn_mfma_f32_16x16x32_bf16(aq, bk, pacc[ni], 0, 0, 0);
    }
  }
  #pragma unroll
  for (int ni = 0; ni < 4; ni++)
    #pragma unroll
    for (int r = 0; r < 4; r++) {
      const int tt = w * 16 + q * 4 + r, ss = ni * 16 + m16;
      float Wts = 0.0f;
      if (ss <= tt) Wts = expf(laS[tt] - laS[ss]) * iS[ss];
      Pl[tt][ss] = f2bf(pacc[ni][r] * Wts);
    }
  __syncthreads();

  // h_intra = P @ V ; M = K'(scaled)^T @ V
  f32x4 hacc[4] = {}, macc[4] = {};
  #pragma unroll
  for (int ks = 0; ks < 2; ks++) {
    const bf16x8 ap = *(const bf16x8*)&Pl[w * 16 + m16][ks * 32 + q * 8];
    const bf16x8 ak = *(const bf16x8*)&KTl[w * 16 + m16][ks * 32 + q * 8];
    #pragma unroll
    for (int ni = 0; ni < 4; ni++) {
      const bf16x8 bv = *(const bf16x8*)&VTl[ni * 16 + m16][ks * 32 + q * 8];
      hacc[ni] = __builtin_amdgcn_mfma_f32_16x16x32_bf16(ap, bv, hacc[ni], 0, 0, 0);
      macc[ni] = __builtin_amdgcn_mfma_f32_16x16x32_bf16(ak, bv, macc[ni], 0, 0, 0);
    }
  }
  const int b = bh >> 4, h = bh & 15;
  #pragma unroll
  for (int ni = 0; ni < 4; ni++)
    #pragma unroll
    for (int r = 0; r < 4; r++) {
      const int tt = w * 16 + q * 4 + r, e = ni * 16 + m16;
      const int tg = c * 64 + tt;
      hseq[((size_t)b * 2048 + tg) * 1024 + h * 64 + e] = f2bf(hacc[ni][r]);
      Mbuf[(((size_t)bh * 32 + c) * 64 + tt) * 64 + e] = macc[ni][r];
    }
}

// ---------------- pass B: inter-chunk state scan (in place: M[c] -> S_prev[c]) ----------------
__global__ __launch_bounds__(256) void passB_k(float* __restrict__ Mbuf,
                                               const float* __restrict__ hidden,
                                               const float* __restrict__ la) {
  const int bh = blockIdx.x >> 4;
  const int e = (blockIdx.x & 15) * 256 + threadIdx.x;
  __shared__ float Gs[32];
  if (threadIdx.x < 32)
    Gs[threadIdx.x] = expf(la[(size_t)bh * 2048 + threadIdx.x * 64 + 63]);
  __syncthreads();
  float st = hidden[(size_t)bh * 4096 + e];
  float* M = &Mbuf[(size_t)bh * 32 * 4096 + e];
  float m_next = M[0];
  #pragma unroll 4
  for (int c = 0; c < 32; c++) {
    const float m_cur = m_next;
    if (c < 31) m_next = M[(size_t)(c + 1) * 4096];
    M[(size_t)c * 4096] = st;
    st = Gs[c] * st + m_cur;
  }
}

// ---------------- pass C: h = o * (h_intra + a_t * q^T S_prev) ----------------
__global__ __launch_bounds__(256) void passC_k(const u16* __restrict__ Qb,
                                               const float* __restrict__ Sprev,
                                               const float* __restrict__ la,
                                               const float* __restrict__ gates,
                                               u16* __restrict__ hseq) {
  __shared__ u16 aQl[64][72], STl[64][72];
  const int tid = threadIdx.x;
  const int bh = blockIdx.x >> 5, c = blockIdx.x & 31;
  const int lane = tid & 63, w = tid >> 6;
  const int q = lane >> 4, m16 = lane & 15;
  const size_t base = ((size_t)bh * 2048 + c * 64) * 64;
  const int tbase = bh * 2048 + c * 64;
  {
    const int s = tid >> 2, db = (tid & 3) * 16;
    const float a_s = expf(la[tbase + s]);
    const uint4 q0 = *(const uint4*)&Qb[base + s * 64 + db];
    const uint4 q1 = *(const uint4*)&Qb[base + s * 64 + db + 8];
    u16 qtmp[16];
    *(uint4*)&qtmp[0] = q0;
    *(uint4*)&qtmp[8] = q1;
    #pragma unroll
    for (int j = 0; j < 16; j++) aQl[s][db + j] = f2bf(a_s * bf2f(qtmp[j]));
    const float* Sp = &Sprev[((size_t)bh * 32 + c) * 4096];
    #pragma unroll
    for (int j = 0; j < 16; j++) STl[db + j][s] = f2bf(Sp[s * 64 + db + j]);
  }
  __syncthreads();
  f32x4 acc[4] = {};
  #pragma unroll
  for (int ks = 0; ks < 2; ks++) {
    const bf16x8 a = *(const bf16x8*)&aQl[w * 16 + m16][ks * 32 + q * 8];
    #pragma unroll
    for (int ni = 0; ni < 4; ni++) {
      const bf16x8 bb = *(const bf16x8*)&STl[ni * 16 + m16][ks * 32 + q * 8];
      acc[ni] = __builtin_amdgcn_mfma_f32_16x16x32_bf16(a, bb, acc[ni], 0, 0, 0);
    }
  }
  const int b = bh >> 4, h = bh & 15;
  #pragma unroll
  for (int ni = 0; ni < 4; ni++)
    #pragma unroll
    for (int r = 0; r < 4; r++) {
      const int tt = w * 16 + q * 4 + r, e = ni * 16 + m16;
      const int tg = c * 64 + tt;
      const float o = gates[(size_t)(128 + bh) * 2048 + tg];  // o-gate
      const size_t idx = ((size_t)b * 2048 + tg) * 1024 + h * 64 + e;
      hseq[idx] = f2bf(o * (bf2f(hseq[idx]) + acc[ni][r]));
    }
}

extern "C" void kernel_launch(void* const* d_in, const int* in_sizes, int n_in,
                              void* d_out, int out_size, void* d_ws, size_t ws_size,
                              hipStream_t stream) {
  (void)in_sizes; (void)n_in; (void)out_size; (void)ws_size;
  const float* x      = (const float*)d_in[0];
  const float* hidden = (const float*)d_in[1];
  const float* w_rms  = (const float*)d_in[2];
  const float* w_qkv  = (const float*)d_in[3];
  const float* w_gate = (const float*)d_in[4];
  const float* w_out  = (const float*)d_in[5];
  float* out = (float*)d_out;

  char* p = (char*)d_ws;
  u16* wqkvT = (u16*)p;  p += (size_t)N1 * 1024 * 2;        // 6.55 MB
  u16* woutT = (u16*)p;  p += (size_t)1024 * 1024 * 2;      // 2.1 MB
  u16* xn    = (u16*)p;  p += (size_t)ROWS * 1024 * 2;      // 16.8 MB
  u16* Qb    = (u16*)p;  p += (size_t)BH * 2048 * 64 * 2;   // 16.8 MB
  u16* Kb    = (u16*)p;  p += (size_t)BH * 2048 * 64 * 2;
  u16* Vb    = (u16*)p;  p += (size_t)BH * 2048 * 64 * 2;
  float* gates = (float*)p; p += (size_t)3 * BH * 2048 * 4; // 1.6 MB
  float* la    = (float*)p; p += (size_t)BH * 2048 * 4;     // 0.5 MB
  float* Mbuf  = (float*)p; p += (size_t)BH * NC * 4096 * 4;// 33.6 MB
  u16* hseq  = (u16*)p;  p += (size_t)ROWS * 1024 * 2;      // 16.8 MB

  transpose_w<<<dim3(96, 32), dim3(32, 8), 0, stream>>>(w_qkv, wqkvT, 1024, 3072);
  transpose_w<<<dim3(32, 32), dim3(32, 8), 0, stream>>>(w_out, woutT, 1024, 1024);
  fill_gateW<<<128, 256, 0, stream>>>(w_gate, wqkvT);
  rmsnorm_k<<<ROWS, 256, 0, stream>>>(x, w_rms, xn);
  gemm_qkv<<<dim3(32, 25), 512, 0, stream>>>(xn, wqkvT, Qb, Kb, Vb, gates);
  passA_k<<<BH * NC, 256, 0, stream>>>(Qb, Kb, Vb, gates, la, Mbuf, hseq);
  passB_k<<<BH * 16, 256, 0, stream>>>(Mbuf, hidden, la);
  passC_k<<<BH * NC, 256, 0, stream>>>(Qb, Mbuf, la, gates, hseq);
  gemm_out<<<dim3(64, 8), 256, 0, stream>>>(hseq, woutT, x, out);
}

// Round 10
// 262.657 us; speedup vs baseline: 1.1006x; 1.0209x over previous
//
#include <hip/hip_runtime.h>
#include <math.h>

typedef unsigned short u16;
typedef unsigned int   u32;
typedef __bf16 bf16x8 __attribute__((ext_vector_type(8)));
typedef float  f32x4  __attribute__((ext_vector_type(4)));

// B=4 S=2048 D=1024 H=16 Dh=64 -> BH=64 chains, 32 chunks of 64
#define NBATCH 4
#define SEQ    2048
#define DIM    1024
#define NH     16
#define BH     64
#define NC     32
#define ROWS   8192
#define N1     3200   /* 3072 qkv cols + 48 gate cols padded to 128 */

__device__ __forceinline__ u16 f2bf(float f) {
  u32 u = __builtin_bit_cast(u32, f);
  u32 r = u + 0x7fffu + ((u >> 16) & 1u);
  return (u16)(r >> 16);
}
__device__ __forceinline__ float bf2f(u16 h) {
  return __builtin_bit_cast(float, (u32)h << 16);
}

// async global->LDS, 16B per lane; LDS dest = wave-uniform base + lane*16
// NOTE: LDS layout is forced (lane-sequential); do NOT permute global order (r6 regression).
__device__ __forceinline__ void gl2lds16(const u16* g, u16* l) {
  __builtin_amdgcn_global_load_lds(
      (const __attribute__((address_space(1))) u32*)g,
      (__attribute__((address_space(3))) u32*)l, 16, 0, 0);
}

// ---------------- weight transpose: Bt[n][k] = W[k][n], fp32 -> bf16 ----------------
__global__ __launch_bounds__(256) void transpose_w(const float* __restrict__ W,
                                                   u16* __restrict__ Bt, int K, int N) {
  __shared__ float tile[32][33];
  const int n0 = blockIdx.x * 32, k0 = blockIdx.y * 32;
  const int tx = threadIdx.x, ty = threadIdx.y;
  #pragma unroll
  for (int i = 0; i < 4; i++)
    tile[ty + i * 8][tx] = W[(size_t)(k0 + ty + i * 8) * N + n0 + tx];
  __syncthreads();
  #pragma unroll
  for (int i = 0; i < 4; i++)
    Bt[(size_t)(n0 + ty + i * 8) * K + k0 + tx] = f2bf(tile[tx][ty + i * 8]);
}

// rows 3072..3199 of wqkvT: gate weights (48 real cols) + zero pad
__global__ __launch_bounds__(256) void fill_gateW(const float* __restrict__ wg,
                                                  u16* __restrict__ Bt) {
  const int g = blockIdx.x;        // 0..127
  const int tid = threadIdx.x;
  #pragma unroll
  for (int kk = 0; kk < 4; kk++) {
    const int k = kk * 256 + tid;
    u16 v = 0;
    if (g < 48) v = f2bf(wg[(size_t)k * 48 + g]);
    Bt[(size_t)(3072 + g) * 1024 + k] = v;
  }
}

// ---------------- RMSNorm: x fp32 -> xn bf16 ----------------
__global__ __launch_bounds__(256) void rmsnorm_k(const float* __restrict__ x,
                                                 const float* __restrict__ w,
                                                 u16* __restrict__ xn) {
  const int row = blockIdx.x, tid = threadIdx.x;
  const float4 xv = *(const float4*)&x[(size_t)row * 1024 + tid * 4];
  float ss = xv.x * xv.x + xv.y * xv.y + xv.z * xv.z + xv.w * xv.w;
  #pragma unroll
  for (int off = 32; off > 0; off >>= 1) ss += __shfl_down(ss, off);
  __shared__ float red[4];
  if ((tid & 63) == 0) red[tid >> 6] = ss;
  __syncthreads();
  const float tot = red[0] + red[1] + red[2] + red[3];
  const float scale = rsqrtf(tot * (1.0f / 1024.0f) + 1e-6f);
  const float4 wv = *(const float4*)&w[tid * 4];
  const u16 o0 = f2bf(xv.x * scale * wv.x), o1 = f2bf(xv.y * scale * wv.y);
  const u16 o2 = f2bf(xv.z * scale * wv.z), o3 = f2bf(xv.w * scale * wv.w);
  uint2 ov;
  ov.x = (u32)o0 | ((u32)o1 << 16);
  ov.y = (u32)o2 | ((u32)o3 << 16);
  *(uint2*)&xn[(size_t)row * 1024 + tid * 4] = ov;
}

// ---------------- MFMA GEMM core: C(256x128), BK=64 as 2x split-half BK=32 ----------------
// (round-9 best: conflicts 7.5M, MfmaUtil 28%)
__device__ __forceinline__ void gemm_core256(const u16* __restrict__ A, const u16* __restrict__ Bt,
                                             int K, int rowBase, int colBase,
                                             u16* As, u16* Bs, f32x4 (&acc)[4][4]) {
  const int tid = threadIdx.x;
  const int lane = tid & 63;
  const int q = lane >> 4, m16 = lane & 15;
  const int wave = tid >> 6;
  const int wm = wave & 3, wn = wave >> 2;
  const u16* gA[4]; u16* lA[4];
  const u16* gB[2]; u16* lB[2];
  #pragma unroll
  for (int j = 0; j < 4; j++) {
    const int c = tid + j * 512;
    const int half = c >> 10, cc = c & 1023;
    gA[j] = &A[(size_t)(rowBase + (cc >> 2)) * K + half * 32 + (cc & 3) * 8];
    lA[j] = As + c * 8;
  }
  #pragma unroll
  for (int j = 0; j < 2; j++) {
    const int c = tid + j * 512;
    const int half = c >> 9, cc = c & 511;
    gB[j] = &Bt[(size_t)(colBase + (cc >> 2)) * K + half * 32 + (cc & 3) * 8];
    lB[j] = Bs + c * 8;
  }
  for (int kb = 0; kb < K / 64; ++kb) {
    __syncthreads();
    #pragma unroll
    for (int j = 0; j < 4; j++) { gl2lds16(gA[j], lA[j]); gA[j] += 64; }
    #pragma unroll
    for (int j = 0; j < 2; j++) { gl2lds16(gB[j], lB[j]); gB[j] += 64; }
    __syncthreads();
    #pragma unroll
    for (int ks = 0; ks < 2; ks++) {
      const int aoff = ks * 8192;   // 256*32
      const int boff = ks * 4096;   // 128*32
      bf16x8 af[4], bfr[4];
      #pragma unroll
      for (int mi = 0; mi < 4; mi++)
        af[mi] = *(const bf16x8*)&As[aoff + (wm * 64 + mi * 16 + m16) * 32 + q * 8];
      #pragma unroll
      for (int ni = 0; ni < 4; ni++)
        bfr[ni] = *(const bf16x8*)&Bs[boff + (wn * 64 + ni * 16 + m16) * 32 + q * 8];
      #pragma unroll
      for (int mi = 0; mi < 4; mi++)
        #pragma unroll
        for (int ni = 0; ni < 4; ni++)
          acc[mi][ni] = __builtin_amdgcn_mfma_f32_16x16x32_bf16(af[mi], bfr[ni], acc[mi][ni], 0, 0, 0);
    }
  }
}

// ---------------- MFMA GEMM core: C(128x128), BK=64 split-half, 256 threads ----------------
__device__ __forceinline__ void gemm_core128(const u16* __restrict__ A, const u16* __restrict__ Bt,
                                             int K, int rowBase, int colBase,
                                             u16* As, u16* Bs, f32x4 (&acc)[4][4]) {
  const int tid = threadIdx.x;
  const int lane = tid & 63;
  const int q = lane >> 4, m16 = lane & 15;
  const int wave = tid >> 6;
  const int wm = wave & 1, wn = wave >> 1;
  const u16* gA[4]; u16* lA[4];
  const u16* gB[4]; u16* lB[4];
  #pragma unroll
  for (int j = 0; j < 4; j++) {
    const int c = tid + j * 256;
    const int half = c >> 9, cc = c & 511;
    gA[j] = &A [(size_t)(rowBase + (cc >> 2)) * K + half * 32 + (cc & 3) * 8];
    lA[j] = As + c * 8;
    gB[j] = &Bt[(size_t)(colBase + (cc >> 2)) * K + half * 32 + (cc & 3) * 8];
    lB[j] = Bs + c * 8;
  }
  for (int kb = 0; kb < K / 64; ++kb) {
    __syncthreads();
    #pragma unroll
    for (int j = 0; j < 4; j++) { gl2lds16(gA[j], lA[j]); gA[j] += 64; }
    #pragma unroll
    for (int j = 0; j < 4; j++) { gl2lds16(gB[j], lB[j]); gB[j] += 64; }
    __syncthreads();
    #pragma unroll
    for (int ks = 0; ks < 2; ks++) {
      const int off = ks * 4096;   // 128*32
      bf16x8 af[4], bfr[4];
      #pragma unroll
      for (int mi = 0; mi < 4; mi++)
        af[mi] = *(const bf16x8*)&As[off + (wm * 64 + mi * 16 + m16) * 32 + q * 8];
      #pragma unroll
      for (int ni = 0; ni < 4; ni++)
        bfr[ni] = *(const bf16x8*)&Bs[off + (wn * 64 + ni * 16 + m16) * 32 + q * 8];
      #pragma unroll
      for (int mi = 0; mi < 4; mi++)
        #pragma unroll
        for (int ni = 0; ni < 4; ni++)
          acc[mi][ni] = __builtin_amdgcn_mfma_f32_16x16x32_bf16(af[mi], bfr[ni], acc[mi][ni], 0, 0, 0);
    }
  }
}

// ---------------- GEMM1: qkv + gates ----------------
__global__ __launch_bounds__(512, 4) void gemm_qkv(const u16* __restrict__ A, const u16* __restrict__ Bt,
                                                   u16* __restrict__ Qb, u16* __restrict__ Kb,
                                                   u16* __restrict__ Vb, float* __restrict__ gates) {
  __shared__ __attribute__((aligned(16))) u16 As[256 * 64];
  __shared__ __attribute__((aligned(16))) u16 Bs[128 * 64];
  f32x4 acc[4][4] = {};
  const int rowBase = blockIdx.x * 256, colBase = blockIdx.y * 128;
  gemm_core256(A, Bt, 1024, rowBase, colBase, As, Bs, acc);
  const int tid = threadIdx.x;
  const int lane = tid & 63, wave = tid >> 6;
  const int q = lane >> 4, m16 = lane & 15;
  const int wm = wave & 3, wn = wave >> 2;
  __syncthreads();   // everyone done reading As before we reuse it as epilogue scratch
  if (colBase < 3072) {
    const int which = colBase >> 10;
    u16* dstBase = (which == 0) ? Qb : ((which == 1) ? Kb : Vb);
    const int b = rowBase >> 11;
    const int h = ((colBase & 1023) >> 6) + wn;
    const int tRow0 = (rowBase & 2047) + wm * 64;
    u16* scratch = As + wave * 1024;   // 16 rows x 64 cols bf16 per wave
    u16* headBase = dstBase + ((size_t)(b * 16 + h)) * 2048 * 64;
    const int rr = lane >> 2, co = (lane & 3) * 16;
    #pragma unroll
    for (int mi = 0; mi < 4; mi++) {
      #pragma unroll
      for (int ni = 0; ni < 4; ni++)
        #pragma unroll
        for (int r = 0; r < 4; r++)
          scratch[(q * 4 + r) * 64 + ni * 16 + m16] = f2bf(acc[mi][ni][r]);
      const uint4 d0 = *(const uint4*)&scratch[rr * 64 + co];
      const uint4 d1 = *(const uint4*)&scratch[rr * 64 + co + 8];
      u16* gp = headBase + (size_t)(tRow0 + mi * 16 + rr) * 64 + co;
      *(uint4*)gp = d0;
      *(uint4*)(gp + 8) = d1;
    }
  } else {
    // gates block: cols 3072..3199, only first 48 meaningful
    #pragma unroll
    for (int ni = 0; ni < 4; ni++) {
      const int c2 = wn * 64 + ni * 16 + m16;
      if (c2 < 48) {
        const int which = c2 >> 4, hh = c2 & 15;
        #pragma unroll
        for (int mi = 0; mi < 4; mi++)
          #pragma unroll
          for (int r = 0; r < 4; r++) {
            const int grow = rowBase + wm * 64 + mi * 16 + q * 4 + r;
            const int b = grow >> 11, t = grow & 2047;
            const float v = acc[mi][ni][r];
            const float g = 1.0f / (1.0f + expf(-(15.0f * tanhf(v * (1.0f / 15.0f)))));
            gates[((size_t)which * 64 + (b * 16 + hh)) * 2048 + t] = g;
          }
      }
    }
  }
}

// ---------------- GEMM2: out = hseq @ woutT + residual ----------------
__global__ __launch_bounds__(256, 4) void gemm_out(const u16* __restrict__ A, const u16* __restrict__ Bt,
                                                   const float* __restrict__ resid,
                                                   float* __restrict__ out) {
  __shared__ __attribute__((aligned(16))) u16 As[128 * 64];
  __shared__ __attribute__((aligned(16))) u16 Bs[128 * 64];
  f32x4 acc[4][4] = {};
  const int rowBase = blockIdx.x * 128, colBase = blockIdx.y * 128;
  gemm_core128(A, Bt, 1024, rowBase, colBase, As, Bs, acc);
  const int tid = threadIdx.x;
  const int lane = tid & 63, wave = tid >> 6;
  const int q = lane >> 4, m16 = lane & 15;
  const int wm = wave & 1, wn = wave >> 1;
  #pragma unroll
  for (int mi = 0; mi < 4; mi++)
    #pragma unroll
    for (int ni = 0; ni < 4; ni++)
      #pragma unroll
      for (int r = 0; r < 4; r++) {
        const int grow = rowBase + wm * 64 + mi * 16 + q * 4 + r;
        const int gcol = colBase + wn * 64 + ni * 16 + m16;
        const size_t idx = (size_t)grow * 1024 + gcol;
        out[idx] = acc[mi][ni][r] + resid[idx];
      }
}

// ---------------- pass A: la-scan + intra-chunk attention + chunk state increment M^T ----------------
// M stored TRANSPOSED [e][d] in bf16 via MFMA operand swap: macc = mfma(bv, ak).
__global__ __launch_bounds__(256) void passA_k(const u16* __restrict__ Qb, const u16* __restrict__ Kb,
                                               const u16* __restrict__ Vb,
                                               const float* __restrict__ gates,
                                               float* __restrict__ la,
                                               u16* __restrict__ Mbuf, u16* __restrict__ hseq) {
  __shared__ u16 Ql[64][72], Kl[64][72], KTl[64][72], VTl[64][72], Pl[64][72];
  __shared__ float laS[64], iS[64];
  const int tid = threadIdx.x;
  const int bh = blockIdx.x >> 5, c = blockIdx.x & 31;
  const int lane = tid & 63, w = tid >> 6;
  const int q = lane >> 4, m16 = lane & 15;
  const size_t base = ((size_t)bh * 2048 + c * 64) * 64;
  const int toff = c * 64;   // time offset within the (bh) chain

  // wave 0: chunk-local cumulative log-f scan (fused la_k)
  if (tid < 64) {
    float lg = logf(gates[(size_t)(64 + bh) * 2048 + toff + tid]);  // f-gate
    #pragma unroll
    for (int off = 1; off < 64; off <<= 1) {
      const float y = __shfl_up(lg, off);
      if (tid >= off) lg += y;
    }
    laS[tid] = lg;
    iS[tid] = gates[(size_t)bh * 2048 + toff + tid];  // i-gate
    la[(size_t)bh * 2048 + toff + tid] = lg;          // for passB/passC
  }
  __syncthreads();

  {
    const int s = tid >> 2, db = (tid & 3) * 16;
    const float wk = expf(laS[63] - laS[s]) * iS[s];
    const uint4 q0 = *(const uint4*)&Qb[base + s * 64 + db];
    const uint4 q1 = *(const uint4*)&Qb[base + s * 64 + db + 8];
    *(uint4*)&Ql[s][db] = q0;
    *(uint4*)&Ql[s][db + 8] = q1;
    const uint4 k0 = *(const uint4*)&Kb[base + s * 64 + db];
    const uint4 k1 = *(const uint4*)&Kb[base + s * 64 + db + 8];
    *(uint4*)&Kl[s][db] = k0;
    *(uint4*)&Kl[s][db + 8] = k1;
    u16 ktmp[16];
    *(uint4*)&ktmp[0] = k0;
    *(uint4*)&ktmp[8] = k1;
    #pragma unroll
    for (int j = 0; j < 16; j++) KTl[db + j][s] = f2bf(wk * bf2f(ktmp[j]));
    const uint4 v0 = *(const uint4*)&Vb[base + s * 64 + db];
    const uint4 v1 = *(const uint4*)&Vb[base + s * 64 + db + 8];
    u16 vtmp[16];
    *(uint4*)&vtmp[0] = v0;
    *(uint4*)&vtmp[8] = v1;
    #pragma unroll
    for (int j = 0; j < 16; j++) VTl[db + j][s] = vtmp[j];
  }
  __syncthreads();

  // P = (Q K^T) * decay-mask
  f32x4 pacc[4] = {};
  #pragma unroll
  for (int ks = 0; ks < 2; ks++) {
    const bf16x8 aq = *(const bf16x8*)&Ql[w * 16 + m16][ks * 32 + q * 8];
    #pragma unroll
    for (int ni = 0; ni < 4; ni++) {
      const bf16x8 bk = *(const bf16x8*)&Kl[ni * 16 + m16][ks * 32 + q * 8];
      pacc[ni] = __builtin_amdgcn_mfma_f32_16x16x32_bf16(aq, bk, pacc[ni], 0, 0, 0);
    }
  }
  #pragma unroll
  for (int ni = 0; ni < 4; ni++)
    #pragma unroll
    for (int r = 0; r < 4; r++) {
      const int tt = w * 16 + q * 4 + r, ss = ni * 16 + m16;
      float Wts = 0.0f;
      if (ss <= tt) Wts = expf(laS[tt] - laS[ss]) * iS[ss];
      Pl[tt][ss] = f2bf(pacc[ni][r] * Wts);
    }
  __syncthreads();

  // h_intra = P @ V ; M^T = V'^T-swap: mfma(bv, ak) -> C[e][d]
  f32x4 hacc[4] = {}, macc[4] = {};
  #pragma unroll
  for (int ks = 0; ks < 2; ks++) {
    const bf16x8 ap = *(const bf16x8*)&Pl[w * 16 + m16][ks * 32 + q * 8];
    const bf16x8 av = *(const bf16x8*)&VTl[w * 16 + m16][ks * 32 + q * 8];
    #pragma unroll
    for (int ni = 0; ni < 4; ni++) {
      const bf16x8 bv = *(const bf16x8*)&VTl[ni * 16 + m16][ks * 32 + q * 8];
      const bf16x8 bk = *(const bf16x8*)&KTl[ni * 16 + m16][ks * 32 + q * 8];
      hacc[ni] = __builtin_amdgcn_mfma_f32_16x16x32_bf16(ap, bv, hacc[ni], 0, 0, 0);
      macc[ni] = __builtin_amdgcn_mfma_f32_16x16x32_bf16(av, bk, macc[ni], 0, 0, 0);
    }
  }
  const int b = bh >> 4, h = bh & 15;
  #pragma unroll
  for (int ni = 0; ni < 4; ni++)
    #pragma unroll
    for (int r = 0; r < 4; r++) {
      const int tt = w * 16 + q * 4 + r, e = ni * 16 + m16;
      const int tg = c * 64 + tt;
      hseq[((size_t)b * 2048 + tg) * 1024 + h * 64 + e] = f2bf(hacc[ni][r]);
      // macc row tt = e-index, col e = d-index (transposed): MbufT[e][d], bf16
      Mbuf[(((size_t)bh * 32 + c) * 64 + tt) * 64 + e] = f2bf(macc[ni][r]);
    }
}

// ---------------- pass B: inter-chunk state scan (in place, bf16: M^T[c] -> S_prev^T[c]) ----------------
__global__ __launch_bounds__(256) void passB_k(u16* __restrict__ Mbuf,
                                               const float* __restrict__ hidden,
                                               const float* __restrict__ la) {
  const int bh = blockIdx.x >> 4;
  const int e = (blockIdx.x & 15) * 256 + threadIdx.x;   // flat idx in 4096 = [e][d] (transposed)
  __shared__ float Gs[32];
  if (threadIdx.x < 32)
    Gs[threadIdx.x] = expf(la[(size_t)bh * 2048 + threadIdx.x * 64 + 63]);
  __syncthreads();
  // hidden is [d][e] (row-major Dh x Dh); transposed flat index:
  const int eRow = e >> 6, dCol = e & 63;
  float st = hidden[(size_t)bh * 4096 + dCol * 64 + eRow];
  u16* M = &Mbuf[(size_t)bh * 32 * 4096 + e];
  float m_next = bf2f(M[0]);
  #pragma unroll 4
  for (int c = 0; c < 32; c++) {
    const float m_cur = m_next;
    if (c < 31) m_next = bf2f(M[(size_t)(c + 1) * 4096]);
    M[(size_t)c * 4096] = f2bf(st);
    st = Gs[c] * st + m_cur;
  }
}

// ---------------- pass C: h = o * (h_intra + a_t * q^T S_prev) ----------------
// SprevT stored [e][d] bf16 -> STl fill is straight vector copies; a_t applied in epilogue.
__global__ __launch_bounds__(256) void passC_k(const u16* __restrict__ Qb,
                                               const u16* __restrict__ SprevT,
                                               const float* __restrict__ la,
                                               const float* __restrict__ gates,
                                               u16* __restrict__ hseq) {
  __shared__ u16 aQl[64][72], STl[64][72];
  __shared__ float laS[64], oS[64];
  const int tid = threadIdx.x;
  const int bh = blockIdx.x >> 5, c = blockIdx.x & 31;
  const int lane = tid & 63, w = tid >> 6;
  const int q = lane >> 4, m16 = lane & 15;
  const size_t base = ((size_t)bh * 2048 + c * 64) * 64;
  const int toff = c * 64;
  if (tid < 64) {
    laS[tid] = la[(size_t)bh * 2048 + toff + tid];
    oS[tid] = gates[(size_t)(128 + bh) * 2048 + toff + tid];  // o-gate
  }
  {
    const int s = tid >> 2, db = (tid & 3) * 16;
    // raw Q copy (a_t applied later)
    *(uint4*)&aQl[s][db]     = *(const uint4*)&Qb[base + s * 64 + db];
    *(uint4*)&aQl[s][db + 8] = *(const uint4*)&Qb[base + s * 64 + db + 8];
    const u16* SpT = &SprevT[((size_t)bh * 32 + c) * 4096];
    *(uint4*)&STl[s][db]     = *(const uint4*)&SpT[s * 64 + db];
    *(uint4*)&STl[s][db + 8] = *(const uint4*)&SpT[s * 64 + db + 8];
  }
  __syncthreads();
  f32x4 acc[4] = {};
  #pragma unroll
  for (int ks = 0; ks < 2; ks++) {
    const bf16x8 a = *(const bf16x8*)&aQl[w * 16 + m16][ks * 32 + q * 8];
    #pragma unroll
    for (int ni = 0; ni < 4; ni++) {
      const bf16x8 bb = *(const bf16x8*)&STl[ni * 16 + m16][ks * 32 + q * 8];
      acc[ni] = __builtin_amdgcn_mfma_f32_16x16x32_bf16(a, bb, acc[ni], 0, 0, 0);
    }
  }
  const int b = bh >> 4, h = bh & 15;
  #pragma unroll
  for (int ni = 0; ni < 4; ni++)
    #pragma unroll
    for (int r = 0; r < 4; r++) {
      const int tt = w * 16 + q * 4 + r, e = ni * 16 + m16;
      const int tg = c * 64 + tt;
      const float a_t = expf(laS[tt]);
      const float o = oS[tt];
      const size_t idx = ((size_t)b * 2048 + tg) * 1024 + h * 64 + e;
      hseq[idx] = f2bf(o * (bf2f(hseq[idx]) + a_t * acc[ni][r]));
    }
}

extern "C" void kernel_launch(void* const* d_in, const int* in_sizes, int n_in,
                              void* d_out, int out_size, void* d_ws, size_t ws_size,
                              hipStream_t stream) {
  (void)in_sizes; (void)n_in; (void)out_size; (void)ws_size;
  const float* x      = (const float*)d_in[0];
  const float* hidden = (const float*)d_in[1];
  const float* w_rms  = (const float*)d_in[2];
  const float* w_qkv  = (const float*)d_in[3];
  const float* w_gate = (const float*)d_in[4];
  const float* w_out  = (const float*)d_in[5];
  float* out = (float*)d_out;

  char* p = (char*)d_ws;
  u16* wqkvT = (u16*)p;  p += (size_t)N1 * 1024 * 2;        // 6.55 MB
  u16* woutT = (u16*)p;  p += (size_t)1024 * 1024 * 2;      // 2.1 MB
  u16* xn    = (u16*)p;  p += (size_t)ROWS * 1024 * 2;      // 16.8 MB
  u16* Qb    = (u16*)p;  p += (size_t)BH * 2048 * 64 * 2;   // 16.8 MB
  u16* Kb    = (u16*)p;  p += (size_t)BH * 2048 * 64 * 2;
  u16* Vb    = (u16*)p;  p += (size_t)BH * 2048 * 64 * 2;
  float* gates = (float*)p; p += (size_t)3 * BH * 2048 * 4; // 1.6 MB
  float* la    = (float*)p; p += (size_t)BH * 2048 * 4;     // 0.5 MB
  u16* Mbuf  = (u16*)p;  p += (size_t)BH * NC * 4096 * 2;   // 16.8 MB (bf16, transposed)
  u16* hseq  = (u16*)p;  p += (size_t)ROWS * 1024 * 2;      // 16.8 MB

  transpose_w<<<dim3(96, 32), dim3(32, 8), 0, stream>>>(w_qkv, wqkvT, 1024, 3072);
  transpose_w<<<dim3(32, 32), dim3(32, 8), 0, stream>>>(w_out, woutT, 1024, 1024);
  fill_gateW<<<128, 256, 0, stream>>>(w_gate, wqkvT);
  rmsnorm_k<<<ROWS, 256, 0, stream>>>(x, w_rms, xn);
  gemm_qkv<<<dim3(32, 25), 512, 0, stream>>>(xn, wqkvT, Qb, Kb, Vb, gates);
  passA_k<<<BH * NC, 256, 0, stream>>>(Qb, Kb, Vb, gates, la, Mbuf, hseq);
  passB_k<<<BH * 16, 256, 0, stream>>>(Mbuf, hidden, la);
  passC_k<<<BH * NC, 256, 0, stream>>>(Qb, Mbuf, la, gates, hseq);
  gemm_out<<<dim3(64, 8), 256, 0, stream>>>(hseq, woutT, x, out);
}